// Round 1
// baseline (9044.392 us; speedup 1.0000x reference)
//
#include <hip/hip_runtime.h>

#define H_ 384
#define W_ 512
#define N_ (H_*W_)        // 196608
#define B_ 2
#define T_ 1048576
#define TMASK_ 0xFFFFFu

__device__ __forceinline__ int prime(int d){
  switch(d){
    case 0: return 73856093;
    case 1: return 19349663;
    case 2: return 83492791;
    case 3: return 49979687;
    default: return 24036583;
  }
}

__device__ __forceinline__ float clampScale(float s){ return fminf(fmaxf(s,1e-5f),1.0f); }

__device__ double blockReduceD(double v){
  __shared__ double sh[256];
  sh[threadIdx.x]=v; __syncthreads();
  for(int s=128;s>0;s>>=1){ if(threadIdx.x<s) sh[threadIdx.x]+=sh[threadIdx.x+s]; __syncthreads(); }
  double r=sh[0]; __syncthreads(); return r;
}
__device__ float blockReduceMaxF(float v){
  __shared__ float sh[256];
  sh[threadIdx.x]=v; __syncthreads();
  for(int s=128;s>0;s>>=1){ if(threadIdx.x<s) sh[threadIdx.x]=fmaxf(sh[threadIdx.x],sh[threadIdx.x+s]); __syncthreads(); }
  float r=sh[0]; __syncthreads(); return r;
}

// ---------------- CNN kernels ----------------

__global__ __launch_bounds__(256) void k_zero_scal(float* scal){
  scal[threadIdx.x] = 0.f;   // 256 floats = 1024 B, covers the double area too
}

// per-batch max of image and feature (values >= 0)
__global__ __launch_bounds__(256) void k_maxes(const float* img, const float* feat, float* scal){
  int idx = blockIdx.x*256 + threadIdx.x;      // grid exactly B*3*N/256
  int b = idx / (3*N_);
  float mi = blockReduceMaxF(img[idx]);
  float mf = blockReduceMaxF(feat[idx]);
  if(threadIdx.x==0){
    atomicMax((int*)&scal[b],   __float_as_int(mi));
    atomicMax((int*)&scal[2+b], __float_as_int(mf));
  }
}

__global__ __launch_bounds__(256) void k_prep(const float* img, const float* pred, const float* scal, float* inp){
  int idx = blockIdx.x*256 + threadIdx.x;
  if(idx >= B_*6*N_) return;
  int pix = idx % N_; int c = (idx/N_)%6; int b = idx/(6*N_);
  float v;
  if(c<3){ float s=clampScale(scal[b]); v = img[((size_t)b*3+c)*N_+pix]/s; }
  else    { v = pred[((size_t)b*3+(c-3))*N_+pix]; }
  inp[idx]=v;
}

// generic direct conv, pad=1, optional clamp(edge)/zero padding, optional dual input (channel concat)
__global__ __launch_bounds__(256) void k_conv(const float* inA, const float* inB, int ICA,
                       const float* wt, const float* bias, float* out,
                       int IC, int IH, int IW, int OC, int OH, int OW,
                       int K, int stride, int clampMode){
  int idx = blockIdx.x*256 + threadIdx.x;
  int total = B_*OC*OH*OW;
  if(idx>=total) return;
  int ox = idx % OW; int t = idx/OW; int oy = t%OH; t/=OH; int oc = t%OC; int b = t/OC;
  int ICB = IC - ICA;
  float acc = bias[oc];
  for(int ic=0; ic<IC; ic++){
    const float* src; int nch, icc;
    if(ic<ICA){ src=inA; nch=ICA; icc=ic; } else { src=inB; nch=ICB; icc=ic-ICA; }
    const float* plane = src + ((size_t)b*nch + icc)*IH*IW;
    for(int ky=0;ky<K;ky++){
      int iy = oy*stride + ky - 1;
      for(int kx=0;kx<K;kx++){
        int ix = ox*stride + kx - 1;
        float v;
        if(clampMode){
          int cy = min(max(iy,0),IH-1), cx = min(max(ix,0),IW-1);
          v = plane[cy*IW+cx];
        } else {
          v = (iy>=0 && iy<IH && ix>=0 && ix<IW) ? plane[iy*IW+ix] : 0.f;
        }
        acc += v * wt[((oc*IC+ic)*K+ky)*K+kx];
      }
    }
  }
  out[idx]=acc;
}

// group norm stats: one block per (b,g); channels of a group are contiguous
__global__ __launch_bounds__(256) void k_gnstats(const float* x, float* stats, int HW){
  int bg = blockIdx.x;               // B*2 blocks
  const float* p = x + (size_t)bg*8*HW;
  int len = 8*HW;
  double s=0.0, s2=0.0;
  for(int i=threadIdx.x;i<len;i+=256){ float v=p[i]; s+=v; s2+=(double)v*(double)v; }
  s = blockReduceD(s); s2 = blockReduceD(s2);
  if(threadIdx.x==0){
    double mean = s/len; double var = s2/len - mean*mean;
    stats[bg*2]   = (float)mean;
    stats[bg*2+1] = (float)(1.0/sqrt(var + 1e-5));
  }
}

__global__ __launch_bounds__(256) void k_gnapply(float* x, const float* stats, const float* gamma, const float* beta, int HW){
  int idx = blockIdx.x*256 + threadIdx.x;
  int total = B_*16*HW;
  if(idx>=total) return;
  int c = (idx/HW)%16; int b = idx/(16*HW);
  int bg = b*2 + (c>>3);
  float v = (x[idx]-stats[bg*2])*stats[bg*2+1]*gamma[c]+beta[c];
  x[idx] = fmaxf(v,0.f);
}

// half-pixel bilinear resize with edge clamp (matches jax.image.resize linear for 2x upsample)
__global__ __launch_bounds__(256) void k_resize(const float* in, float* out, int C, int IH, int IW, int OH, int OW){
  int idx = blockIdx.x*256 + threadIdx.x;
  int total = B_*C*OH*OW;
  if(idx>=total) return;
  int ox = idx%OW; int t=idx/OW; int oy=t%OH; t/=OH;   // t = b*C+c
  const float* plane = in + (size_t)t*IH*IW;
  float sy = (float)IH/(float)OH, sx=(float)IW/(float)OW;
  float fy = (oy+0.5f)*sy-0.5f, fx=(ox+0.5f)*sx-0.5f;
  float fy0 = floorf(fy), fx0=floorf(fx);
  float ty = fy-fy0, tx = fx-fx0;
  int y0 = min(max((int)fy0,0),IH-1), y1 = min(max((int)fy0+1,0),IH-1);
  int x0 = min(max((int)fx0,0),IW-1), x1 = min(max((int)fx0+1,0),IW-1);
  float v00=plane[y0*IW+x0], v01=plane[y0*IW+x1], v10=plane[y1*IW+x0], v11=plane[y1*IW+x1];
  out[idx] = (1.f-ty)*((1.f-tx)*v00+tx*v01) + ty*((1.f-tx)*v10+tx*v11);
}

// conf head: 3x3 edge-padded conv -> 0.5*(tanh+1), track global max
__global__ __launch_bounds__(256) void k_conv5(const float* in, const float* wf, const float* bf,
                                               float* confr, float* scal){
  int idx = blockIdx.x*256 + threadIdx.x;   // grid exactly B*N/256
  int pix = idx % N_; int b = idx / N_;
  int oy = pix / W_, ox = pix % W_;
  float acc = bf[0];
  for(int ic=0; ic<16; ic++){
    const float* plane = in + ((size_t)b*16+ic)*N_;
    for(int ky=0;ky<3;ky++){
      int iy = min(max(oy+ky-1,0),H_-1);
      for(int kx=0;kx<3;kx++){
        int ix = min(max(ox+kx-1,0),W_-1);
        acc += plane[iy*W_+ix]*wf[(ic*3+ky)*3+kx];
      }
    }
  }
  float c = 0.5f*(tanhf(acc)+1.0f);
  confr[idx]=c;
  float mx = blockReduceMaxF(c);
  if(threadIdx.x==0) atomicMax((int*)&scal[4], __float_as_int(mx));
}

__global__ __launch_bounds__(256) void k_confnorm(const float* confr, const float* scal, float* confout){
  int idx = blockIdx.x*256 + threadIdx.x;
  if(idx>=B_*N_) return;
  confout[idx] = confr[idx] / fmaxf(scal[4], 1e-5f);
}

// ---------------- bilateral solver kernels ----------------

__global__ __launch_bounds__(256) void k_initslots(int* winner, int* occ, float* m, float* wsplat,
                                                   float* vb, double* scalD){
  int t = blockIdx.x*256 + threadIdx.x;     // grid exactly T/256
  winner[t]=-1; occ[t]=0; m[t]=0.f; wsplat[t]=0.f;
  vb[3*t]=0.f; vb[3*t+1]=0.f; vb[3*t+2]=0.f;
  if(blockIdx.x==0 && threadIdx.x<16) scalD[threadIdx.x]=0.0;
}

__global__ __launch_bounds__(256) void k_pixel(const float* feat, const float* pred, const float* conf,
                        const float* scal, int b, int* hpix, short* cpix, int* winner, int* occ,
                        float* m, float* wsplat, float* vb){
  int pix = blockIdx.x*256 + threadIdx.x;
  if(pix>=N_) return;
  int y = pix / W_, x = pix % W_;
  float sF = clampScale(scal[2+b]);
  const float* fb = feat + (size_t)b*3*N_;
  // exact reference eval order, no FMA contraction (coords are integer-binned)
  float R  = __fmul_rn(__fdiv_rn(fb[pix],      sF), 255.0f);
  float G  = __fmul_rn(__fdiv_rn(fb[N_+pix],   sF), 255.0f);
  float Bl = __fmul_rn(__fdiv_rn(fb[2*N_+pix], sF), 255.0f);
  float Y = __fadd_rn(__fadd_rn(__fadd_rn(__fmul_rn(0.299f,R),     __fmul_rn(0.587f,G)),  __fmul_rn(0.114f,Bl)), 0.0f);
  float U = __fadd_rn(__fadd_rn(__fadd_rn(__fmul_rn(-0.168736f,R), __fmul_rn(-0.331264f,G)), __fmul_rn(0.5f,Bl)), 128.0f);
  float V = __fadd_rn(__fadd_rn(__fadd_rn(__fmul_rn(0.5f,R),       __fmul_rn(-0.418688f,G)), __fmul_rn(-0.081312f,Bl)), 128.0f);
  int c[5];
  c[0] = (int)floorf(__fdiv_rn((float)x, 7.0f));
  c[1] = (int)floorf(__fdiv_rn((float)y, 7.0f));
  c[2] = (int)floorf(__fdiv_rn(Y, 8.0f));
  c[3] = (int)floorf(__fdiv_rn(U, 2.0f));
  c[4] = (int)floorf(__fdiv_rn(V, 2.0f));
  unsigned hh = 0;
  #pragma unroll
  for(int d=0;d<5;d++) hh += (unsigned)c[d]*(unsigned)prime(d);
  hh &= TMASK_;
  hpix[pix]=(int)hh;
  #pragma unroll
  for(int d=0;d<5;d++) cpix[pix*5+d]=(short)c[d];
  atomicMax(&winner[hh], pix);     // last (highest-index) scatter wins, matches XLA
  occ[hh]=1;
  atomicAdd(&m[hh],1.0f);
  float w = conf[pix];
  atomicAdd(&wsplat[hh], w);
  const float* pb = pred + (size_t)b*3*N_;
  atomicAdd(&vb[hh*3+0], __fmul_rn(w, pb[pix]));
  atomicAdd(&vb[hh*3+1], __fmul_rn(w, pb[N_+pix]));
  atomicAdd(&vb[hh*3+2], __fmul_rn(w, pb[2*N_+pix]));
}

__global__ __launch_bounds__(256) void k_ctab(const int* winner, const short* cpix, short* ctab){
  int t = blockIdx.x*256 + threadIdx.x;
  int wi = winner[t];
  if(wi>=0){
    #pragma unroll
    for(int d=0;d<5;d++) ctab[t*5+d]=cpix[wi*5+d];
  }
}

// neighbor validity bits; exploits hash(ctab[t]) == t for occupied slots
__global__ __launch_bounds__(256) void k_neighbors(const int* occ, const short* ctab, unsigned* val, float* n0){
  int t = blockIdx.x*256 + threadIdx.x;
  int o = occ[t];
  n0[t] = o ? 1.0f : 0.0f;
  unsigned bits = 0;
  if(o){
    int c[5];
    #pragma unroll
    for(int d=0;d<5;d++) c[d]=(int)ctab[t*5+d];
    #pragma unroll
    for(int j=0;j<10;j++){
      int d=j>>1; int off=(j&1)?1:-1;
      unsigned nh = ((unsigned)t + (unsigned)(off*prime(d))) & TMASK_;
      if(occ[nh]){
        bool eq=true;
        #pragma unroll
        for(int k2=0;k2<5;k2++){
          int expect = c[k2] + ((k2==d)?off:0);
          eq = eq && ((int)ctab[nh*5+k2]==expect);
        }
        if(eq) bits |= (1u<<j);
      }
    }
    bits |= (1u<<10);   // occupied flag
  }
  val[t]=bits;
}

__global__ __launch_bounds__(256) void k_bisto(const float* ns, float* nd, const float* m, const unsigned* val){
  int t = blockIdx.x*256 + threadIdx.x;
  unsigned u = val[t];
  float nv = ns[t];
  float bv = 0.f;
  if(u & 1024u){
    bv = 10.f*nv;
    #pragma unroll
    for(int j=0;j<10;j++){
      if((u>>j)&1u){
        int d=j>>1; int off=(j&1)?1:-1;
        unsigned nh = ((unsigned)t + (unsigned)(off*prime(d))) & TMASK_;
        bv += ns[nh];
      }
    }
  }
  nd[t] = sqrtf(nv*m[t]/(bv+1e-12f));
}

__global__ __launch_bounds__(256) void k_mfinal(const float* n0, float* m, const float* wsplat,
                                                float* minv, const unsigned* val){
  int t = blockIdx.x*256 + threadIdx.x;
  unsigned u=val[t];
  float nv=n0[t];
  float bv=0.f;
  if(u&1024u){
    bv = 10.f*nv;
    #pragma unroll
    for(int j=0;j<10;j++){
      if((u>>j)&1u){
        int d=j>>1; int off=(j&1)?1:-1;
        unsigned nh = ((unsigned)t + (unsigned)(off*prime(d))) & TMASK_;
        bv += n0[nh];
      }
    }
  }
  float mn = nv*bv;
  m[t]=mn;
  float Ad = fmaxf(200.0f*(mn - 10.f*nv*nv) + wsplat[t], 1e-5f);
  minv[t] = 1.0f/Ad;
}

__global__ __launch_bounds__(256) void k_x0(const float* vb, const float* wsplat, float* x){
  int i = blockIdx.x*256 + threadIdx.x;   // grid exactly 3T/256
  int t = i/3;
  x[i] = vb[i]/(wsplat[t]+1e-12f);
}

// Ap = LAM*(m*v - n*blur(n*v)) + wsplat*v ; optional fused p.Ap per-channel reduction
__global__ __launch_bounds__(256) void k_A(const float* v, float* Ap, const float* n0, const float* m,
                    const float* wsplat, const unsigned* val, double* red){
  int t = blockIdx.x*256 + threadIdx.x;   // grid exactly T/256
  unsigned u=val[t];
  float nv=n0[t];
  float v0=v[3*t], v1=v[3*t+1], v2=v[3*t+2];
  float s0=0.f,s1=0.f,s2=0.f;
  if(u&1024u){
    s0=10.f*nv*v0; s1=10.f*nv*v1; s2=10.f*nv*v2;
    #pragma unroll
    for(int j=0;j<10;j++){
      if((u>>j)&1u){
        int d=j>>1; int off=(j&1)?1:-1;
        unsigned nh = ((unsigned)t + (unsigned)(off*prime(d))) & TMASK_;
        float nn = n0[nh];
        s0 += nn*v[3*nh]; s1 += nn*v[3*nh+1]; s2 += nn*v[3*nh+2];
      }
    }
  }
  float mm=m[t], ws=wsplat[t];
  float A0 = 200.f*(mm*v0 - nv*s0) + ws*v0;
  float A1 = 200.f*(mm*v1 - nv*s1) + ws*v1;
  float A2 = 200.f*(mm*v2 - nv*s2) + ws*v2;
  Ap[3*t]=A0; Ap[3*t+1]=A1; Ap[3*t+2]=A2;
  if(red){
    double p0 = (double)v0*A0; double p1=(double)v1*A1; double p2=(double)v2*A2;
    p0=blockReduceD(p0); p1=blockReduceD(p1); p2=blockReduceD(p2);
    if(threadIdx.x==0){ atomicAdd(&red[0],p0); atomicAdd(&red[1],p1); atomicAdd(&red[2],p2); }
  }
}

__global__ __launch_bounds__(256) void k_r0(const float* vb, const float* Ap, const float* minv,
                     float* r, float* z, float* p, double* red){
  int t = blockIdx.x*256 + threadIdx.x;   // grid exactly T/256
  float mi = minv[t];
  double acc[3];
  #pragma unroll
  for(int c=0;c<3;c++){
    float rr = vb[3*t+c]-Ap[3*t+c];
    float zz = mi*rr;
    r[3*t+c]=rr; z[3*t+c]=zz; p[3*t+c]=zz;
    acc[c] = (double)rr*(double)zz;
  }
  acc[0]=blockReduceD(acc[0]); acc[1]=blockReduceD(acc[1]); acc[2]=blockReduceD(acc[2]);
  if(threadIdx.x==0){ atomicAdd(&red[0],acc[0]); atomicAdd(&red[1],acc[1]); atomicAdd(&red[2],acc[2]); }
}

__global__ __launch_bounds__(256) void k_zero6(double* a, double* b){
  if(threadIdx.x<3){ a[threadIdx.x]=0.0; b[threadIdx.x]=0.0; }
}

__global__ __launch_bounds__(256) void k_upd1(float* x, float* r, float* z, const float* p, const float* Ap,
                       const float* minv, const double* rzCur, const double* pAp, double* rzNew){
  int t = blockIdx.x*256 + threadIdx.x;   // grid exactly T/256
  float mi=minv[t];
  float alpha[3];
  #pragma unroll
  for(int c=0;c<3;c++) alpha[c] = (float)rzCur[c] / ((float)pAp[c] + 1e-12f);
  double acc[3];
  #pragma unroll
  for(int c=0;c<3;c++){
    float xx = x[3*t+c] + alpha[c]*p[3*t+c];
    float rr = r[3*t+c] - alpha[c]*Ap[3*t+c];
    float zz = mi*rr;
    x[3*t+c]=xx; r[3*t+c]=rr; z[3*t+c]=zz;
    acc[c] = (double)rr*(double)zz;
  }
  acc[0]=blockReduceD(acc[0]); acc[1]=blockReduceD(acc[1]); acc[2]=blockReduceD(acc[2]);
  if(threadIdx.x==0){ atomicAdd(&rzNew[0],acc[0]); atomicAdd(&rzNew[1],acc[1]); atomicAdd(&rzNew[2],acc[2]); }
}

__global__ __launch_bounds__(256) void k_upd2(float* p, const float* z, const double* rzNew, const double* rzCur){
  int i = blockIdx.x*256 + threadIdx.x;   // grid exactly 3T/256
  int c = i%3;
  float beta = (float)rzNew[c] / ((float)rzCur[c] + 1e-12f);
  p[i] = z[i] + beta*p[i];
}

__global__ __launch_bounds__(256) void k_out(const float* x, const int* hpix, float* out, int b){
  int pix = blockIdx.x*256 + threadIdx.x;
  if(pix>=N_) return;
  int hh = hpix[pix];
  #pragma unroll
  for(int c=0;c<3;c++)
    out[((size_t)(b*3+c))*N_+pix] = x[3*hh+c];
}

// ---------------- host launcher ----------------

extern "C" void kernel_launch(void* const* d_in, const int* in_sizes, int n_in,
                              void* d_out, int out_size, void* d_ws, size_t ws_size,
                              hipStream_t stream){
  const float* image=(const float*)d_in[0];
  const float* feature=(const float*)d_in[1];
  const float* pred=(const float*)d_in[2];
  const float* w1=(const float*)d_in[3];  const float* b1=(const float*)d_in[4];
  const float* g1=(const float*)d_in[5];  const float* be1=(const float*)d_in[6];
  const float* w2=(const float*)d_in[7];  const float* b2=(const float*)d_in[8];
  const float* g2=(const float*)d_in[9];  const float* be2=(const float*)d_in[10];
  const float* wd1=(const float*)d_in[11];const float* bd1=(const float*)d_in[12];
  const float* gd1=(const float*)d_in[13];const float* bed1=(const float*)d_in[14];
  const float* wd2=(const float*)d_in[15];const float* bd2=(const float*)d_in[16];
  const float* gd2=(const float*)d_in[17];const float* bed2=(const float*)d_in[18];
  const float* wf=(const float*)d_in[19]; const float* bf=(const float*)d_in[20];
  float* outp=(float*)d_out;                          // (B,3,H,W)
  float* confout = outp + (size_t)B_*3*N_;            // (B,1,H,W)

  char* wsb=(char*)d_ws;
  float* scal=(float*)wsb;                            // [0..1]=sImg, [2..3]=sFeat, [4]=cmax, [8..15]=gn stats
  double* scalD=(double*)(wsb+512);                   // CG scalars: rzA[3], rzB[3], pAp[3]
  size_t off=1024;
  auto alloc=[&](size_t bytes)->char*{ char* pp=wsb+off; off=(off+bytes+255)&~(size_t)255; return pp; };

  // CNN region (dead once conf is in d_out; bilateral region overlaps it)
  float* inp  =(float*)alloc((size_t)B_*6*N_*4);
  float* x1   =(float*)alloc((size_t)B_*16*192*256*4);
  float* x2   =(float*)alloc((size_t)B_*16*96*128*4);
  float* dx1  =(float*)alloc((size_t)B_*16*96*128*4);
  float* dx1r =(float*)alloc((size_t)B_*16*192*256*4);
  float* dx2  =(float*)alloc((size_t)B_*16*192*256*4);
  float* dx2r =(float*)alloc((size_t)B_*16*N_*4);
  float* confr=(float*)alloc((size_t)B_*N_*4);

  // bilateral region (reset offset: CNN buffers are dead by the time these are written)
  off = 1024;
  int*   hpix  =(int*)  alloc((size_t)N_*4);
  short* cpix  =(short*)alloc((size_t)N_*5*2);
  int*   winner=(int*)  alloc((size_t)T_*4);
  int*   occ   =(int*)  alloc((size_t)T_*4);
  short* ctab  =(short*)alloc((size_t)T_*5*2);
  float* m     =(float*)alloc((size_t)T_*4);
  float* nA    =(float*)alloc((size_t)T_*4);
  float* nB    =(float*)alloc((size_t)T_*4);
  float* minv  =(float*)alloc((size_t)T_*4);
  float* wsplat=(float*)alloc((size_t)T_*4);
  float* vb    =(float*)alloc((size_t)T_*3*4);
  float* vx    =(float*)alloc((size_t)T_*3*4);
  float* vr    =(float*)alloc((size_t)T_*3*4);
  float* vz    =(float*)alloc((size_t)T_*3*4);
  float* vp    =(float*)alloc((size_t)T_*3*4);
  float* vAp   =(float*)alloc((size_t)T_*3*4);
  unsigned* val=(unsigned*)winner;    // alias: winner dead after k_ctab, val written in k_neighbors

  dim3 blk(256);
  const int GT = T_/256, G3T = 3*T_/256, GN = N_/256;

  // ---- CNN ----
  k_zero_scal<<<1,blk,0,stream>>>(scal);
  k_maxes<<<(B_*3*N_)/256,blk,0,stream>>>(image,feature,scal);
  k_prep<<<(B_*6*N_)/256,blk,0,stream>>>(image,pred,scal,inp);

  k_conv<<<(B_*16*192*256)/256,blk,0,stream>>>(inp,nullptr,6, w1,b1,x1, 6,H_,W_, 16,192,256, 4,2,1);
  k_gnstats<<<4,blk,0,stream>>>(x1, scal+8, 192*256);
  k_gnapply<<<(B_*16*192*256)/256,blk,0,stream>>>(x1, scal+8, g1, be1, 192*256);

  k_conv<<<(B_*16*96*128)/256,blk,0,stream>>>(x1,nullptr,16, w2,b2,x2, 16,192,256, 16,96,128, 4,2,1);
  k_gnstats<<<4,blk,0,stream>>>(x2, scal+8, 96*128);
  k_gnapply<<<(B_*16*96*128)/256,blk,0,stream>>>(x2, scal+8, g2, be2, 96*128);

  k_conv<<<(B_*16*96*128)/256,blk,0,stream>>>(x2,nullptr,16, wd1,bd1,dx1, 16,96,128, 16,96,128, 3,1,0);
  k_gnstats<<<4,blk,0,stream>>>(dx1, scal+8, 96*128);
  k_gnapply<<<(B_*16*96*128)/256,blk,0,stream>>>(dx1, scal+8, gd1, bed1, 96*128);

  k_resize<<<(B_*16*192*256)/256,blk,0,stream>>>(dx1, dx1r, 16, 96,128, 192,256);

  k_conv<<<(B_*16*192*256)/256,blk,0,stream>>>(dx1r, x1, 16, wd2,bd2,dx2, 32,192,256, 16,192,256, 3,1,0);
  k_gnstats<<<4,blk,0,stream>>>(dx2, scal+8, 192*256);
  k_gnapply<<<(B_*16*192*256)/256,blk,0,stream>>>(dx2, scal+8, gd2, bed2, 192*256);

  k_resize<<<(B_*16*N_)/256,blk,0,stream>>>(dx2, dx2r, 16, 192,256, 384,512);

  k_conv5<<<(B_*N_)/256,blk,0,stream>>>(dx2r, wf, bf, confr, scal);
  k_confnorm<<<(B_*N_)/256,blk,0,stream>>>(confr, scal, confout);

  // ---- bilateral solver per batch ----
  for(int b=0;b<B_;b++){
    const float* confb = confout + (size_t)b*N_;
    k_initslots<<<GT,blk,0,stream>>>(winner,occ,m,wsplat,vb,scalD);
    k_pixel<<<GN,blk,0,stream>>>(feature,pred,confb,scal,b,hpix,cpix,winner,occ,m,wsplat,vb);
    k_ctab<<<GT,blk,0,stream>>>(winner,cpix,ctab);
    k_neighbors<<<GT,blk,0,stream>>>(occ,ctab,val,nA);

    float* nbuf[2] = {nA, nB};
    for(int it=0; it<10; ++it)
      k_bisto<<<GT,blk,0,stream>>>(nbuf[it&1], nbuf[(it+1)&1], m, val);
    float* nfin = nbuf[0];   // 10 iterations -> ends back in nA

    k_mfinal<<<GT,blk,0,stream>>>(nfin, m, wsplat, minv, val);
    k_x0<<<G3T,blk,0,stream>>>(vb, wsplat, vx);
    k_A<<<GT,blk,0,stream>>>(vx, vAp, nfin, m, wsplat, val, nullptr);
    k_r0<<<GT,blk,0,stream>>>(vb, vAp, minv, vr, vz, vp, scalD);   // rz0 -> scalD[0..2]

    double* rzs[2] = {scalD, scalD+3};
    double* pAp = scalD+6;
    for(int it=0; it<12; ++it){
      double* cur = rzs[it&1];
      double* nxt = rzs[(it+1)&1];
      k_zero6<<<1,64,0,stream>>>(nxt, pAp);
      k_A<<<GT,blk,0,stream>>>(vp, vAp, nfin, m, wsplat, val, pAp);
      k_upd1<<<GT,blk,0,stream>>>(vx, vr, vz, vp, vAp, minv, cur, pAp, nxt);
      k_upd2<<<G3T,blk,0,stream>>>(vp, vz, nxt, cur);
    }
    k_out<<<GN,blk,0,stream>>>(vx, hpix, outp, b);
  }
  (void)in_sizes; (void)n_in; (void)out_size; (void)ws_size;
}

// Round 2
// 2202.209 us; speedup vs baseline: 4.1070x; 4.1070x over previous
//
#include <hip/hip_runtime.h>

#define H_ 384
#define W_ 512
#define N_ (H_*W_)        // 196608
#define B_ 2
#define T_ 1048576
#define TMASK_ 0xFFFFFu
#define GT_ (T_/256)      // 4096
#define GM_ (N_/256)      // 768
#define CH_ 16            // channel stride (doubles) for padded accumulators (128B)

__device__ __forceinline__ int prime(int d){
  switch(d){
    case 0: return 73856093;
    case 1: return 19349663;
    case 2: return 83492791;
    case 3: return 49979687;
    default: return 24036583;
  }
}

__device__ __forceinline__ float clampScale(float s){ return fminf(fmaxf(s,1e-5f),1.0f); }

__device__ __forceinline__ double blockReduceD(double v){
  __shared__ double sh[4];
  for(int s=32;s>0;s>>=1) v += __shfl_down(v,s,64);
  int lane=threadIdx.x&63, w=threadIdx.x>>6;
  if(lane==0) sh[w]=v;
  __syncthreads();
  double r = sh[0]+sh[1]+sh[2]+sh[3];
  __syncthreads();
  return r;
}
__device__ __forceinline__ float blockReduceMaxF(float v){
  __shared__ float sh[4];
  for(int s=32;s>0;s>>=1) v = fmaxf(v,__shfl_down(v,s,64));
  int lane=threadIdx.x&63, w=threadIdx.x>>6;
  if(lane==0) sh[w]=v;
  __syncthreads();
  float r = fmaxf(fmaxf(sh[0],sh[1]),fmaxf(sh[2],sh[3]));
  __syncthreads();
  return r;
}

// ---------------- CNN kernels ----------------

__global__ __launch_bounds__(256) void k_zero_scal(float* scal, int* count, double* scalD){
  int tid=threadIdx.x;
  if(tid<64) scal[tid]=0.f;
  if(tid==0) *count=0;
  scalD[2048+tid]=0.0;        // GN accumulators (512 doubles)
  scalD[2048+256+tid]=0.0;
}

__global__ __launch_bounds__(256) void k_maxes(const float* img, const float* feat, float* scal){
  int idx = blockIdx.x*256 + threadIdx.x;      // grid exactly B*3*N/256
  int b = idx / (3*N_);
  float mi = blockReduceMaxF(img[idx]);
  float mf = blockReduceMaxF(feat[idx]);
  if(threadIdx.x==0){
    atomicMax((int*)&scal[b],   __float_as_int(mi));
    atomicMax((int*)&scal[2+b], __float_as_int(mf));
  }
}

__global__ __launch_bounds__(256) void k_prep(const float* img, const float* pred, const float* scal, float* inp){
  int idx = blockIdx.x*256 + threadIdx.x;      // grid exactly B*6*N/256
  int pix = idx % N_; int c = (idx/N_)%6; int b = idx/(6*N_);
  float v;
  if(c<3){ float s=clampScale(scal[b]); v = img[((size_t)b*3+c)*N_+pix]/s; }
  else    { v = pred[((size_t)b*3+(c-3))*N_+pix]; }
  inp[idx]=v;
}

__global__ __launch_bounds__(256) void k_conv(const float* inA, const float* inB, int ICA,
                       const float* wt, const float* bias, float* out,
                       int IC, int IH, int IW, int OC, int OH, int OW,
                       int K, int stride, int clampMode){
  int idx = blockIdx.x*256 + threadIdx.x;
  int total = B_*OC*OH*OW;
  if(idx>=total) return;
  int ox = idx % OW; int t = idx/OW; int oy = t%OH; t/=OH; int oc = t%OC; int b = t/OC;
  int ICB = IC - ICA;
  float acc = bias[oc];
  for(int ic=0; ic<IC; ic++){
    const float* src; int nch, icc;
    if(ic<ICA){ src=inA; nch=ICA; icc=ic; } else { src=inB; nch=ICB; icc=ic-ICA; }
    const float* plane = src + ((size_t)b*nch + icc)*IH*IW;
    for(int ky=0;ky<K;ky++){
      int iy = oy*stride + ky - 1;
      for(int kx=0;kx<K;kx++){
        int ix = ox*stride + kx - 1;
        float v;
        if(clampMode){
          int cy = min(max(iy,0),IH-1), cx = min(max(ix,0),IW-1);
          v = plane[cy*IW+cx];
        } else {
          v = (iy>=0 && iy<IH && ix>=0 && ix<IW) ? plane[iy*IW+ix] : 0.f;
        }
        acc += v * wt[((oc*IC+ic)*K+ky)*K+kx];
      }
    }
  }
  out[idx]=acc;
}

// grid-wide GN partial sums: acc layout acc[bg*32 + 0]=sum, acc[bg*32+16]=sumsq
__global__ __launch_bounds__(256) void k_gnpartial(const float* x, double* acc, int HW){
  int idx = blockIdx.x*256 + threadIdx.x;      // grid exactly B*16*HW/256
  int c = (idx/HW)%16; int b = idx/(16*HW);
  int bg = b*2 + (c>>3);
  float v = x[idx];
  double s  = blockReduceD((double)v);
  double s2 = blockReduceD((double)v*(double)v);
  if(threadIdx.x==0){
    atomicAdd(&acc[bg*32],    s);
    atomicAdd(&acc[bg*32+16], s2);
  }
}

__global__ __launch_bounds__(256) void k_gnapply(float* x, const double* acc, const float* gamma, const float* beta, int HW){
  int idx = blockIdx.x*256 + threadIdx.x;      // grid exactly B*16*HW/256
  int c = (idx/HW)%16; int b = idx/(16*HW);
  int bg = b*2 + (c>>3);
  double len = 8.0*(double)HW;
  double s = acc[bg*32], s2 = acc[bg*32+16];
  double mean = s/len;
  double var = s2/len - mean*mean;
  float rstd = (float)(1.0/sqrt(var + 1e-5));
  float mf = (float)mean;
  float v = (x[idx]-mf)*rstd*gamma[c]+beta[c];
  x[idx] = fmaxf(v,0.f);
}

__global__ __launch_bounds__(256) void k_resize(const float* in, float* out, int C, int IH, int IW, int OH, int OW){
  int idx = blockIdx.x*256 + threadIdx.x;
  int total = B_*C*OH*OW;
  if(idx>=total) return;
  int ox = idx%OW; int t=idx/OW; int oy=t%OH; t/=OH;   // t = b*C+c
  const float* plane = in + (size_t)t*IH*IW;
  float sy = (float)IH/(float)OH, sx=(float)IW/(float)OW;
  float fy = (oy+0.5f)*sy-0.5f, fx=(ox+0.5f)*sx-0.5f;
  float fy0 = floorf(fy), fx0=floorf(fx);
  float ty = fy-fy0, tx = fx-fx0;
  int y0 = min(max((int)fy0,0),IH-1), y1 = min(max((int)fy0+1,0),IH-1);
  int x0 = min(max((int)fx0,0),IW-1), x1 = min(max((int)fx0+1,0),IW-1);
  float v00=plane[y0*IW+x0], v01=plane[y0*IW+x1], v10=plane[y1*IW+x0], v11=plane[y1*IW+x1];
  out[idx] = (1.f-ty)*((1.f-tx)*v00+tx*v01) + ty*((1.f-tx)*v10+tx*v11);
}

__global__ __launch_bounds__(256) void k_conv5(const float* in, const float* wf, const float* bf,
                                               float* confr, float* scal){
  int idx = blockIdx.x*256 + threadIdx.x;   // grid exactly B*N/256
  int pix = idx % N_; int b = idx / N_;
  int oy = pix / W_, ox = pix % W_;
  float acc = bf[0];
  for(int ic=0; ic<16; ic++){
    const float* plane = in + ((size_t)b*16+ic)*N_;
    for(int ky=0;ky<3;ky++){
      int iy = min(max(oy+ky-1,0),H_-1);
      for(int kx=0;kx<3;kx++){
        int ix = min(max(ox+kx-1,0),W_-1);
        acc += plane[iy*W_+ix]*wf[(ic*3+ky)*3+kx];
      }
    }
  }
  float c = 0.5f*(tanhf(acc)+1.0f);
  confr[idx]=c;
  float mx = blockReduceMaxF(c);
  if(threadIdx.x==0) atomicMax((int*)&scal[4], __float_as_int(mx));
}

__global__ __launch_bounds__(256) void k_confnorm(const float* confr, const float* scal, float* confout){
  int idx = blockIdx.x*256 + threadIdx.x;   // grid exactly B*N/256
  confout[idx] = confr[idx] / fmaxf(scal[4], 1e-5f);
}

// ---------------- bilateral solver kernels ----------------

__global__ __launch_bounds__(256) void k_initslots(int* winner, float* m, float* wsplat,
                                                   float* vb, double* scalD, int* count){
  int t = blockIdx.x*256 + threadIdx.x;     // grid exactly T/256
  winner[t]=-1; m[t]=0.f; wsplat[t]=0.f;
  vb[3*t]=0.f; vb[3*t+1]=0.f; vb[3*t+2]=0.f;
  if(t<2048) scalD[t]=0.0;                  // CG scalar accumulators
  if(t==0) *count=0;
}

__global__ __launch_bounds__(256) void k_pixel(const float* feat, const float* pred, const float* conf,
                        const float* scal, int b, int* hpix, short* cpix, int* winner,
                        float* m, float* wsplat, float* vb){
  int pix = blockIdx.x*256 + threadIdx.x;   // grid exactly N/256
  int y = pix / W_, x = pix % W_;
  float sF = clampScale(scal[2+b]);
  const float* fb = feat + (size_t)b*3*N_;
  // exact reference eval order, no FMA contraction (coords are integer-binned)
  float R  = __fmul_rn(__fdiv_rn(fb[pix],      sF), 255.0f);
  float G  = __fmul_rn(__fdiv_rn(fb[N_+pix],   sF), 255.0f);
  float Bl = __fmul_rn(__fdiv_rn(fb[2*N_+pix], sF), 255.0f);
  float Y = __fadd_rn(__fadd_rn(__fadd_rn(__fmul_rn(0.299f,R),     __fmul_rn(0.587f,G)),  __fmul_rn(0.114f,Bl)), 0.0f);
  float U = __fadd_rn(__fadd_rn(__fadd_rn(__fmul_rn(-0.168736f,R), __fmul_rn(-0.331264f,G)), __fmul_rn(0.5f,Bl)), 128.0f);
  float V = __fadd_rn(__fadd_rn(__fadd_rn(__fmul_rn(0.5f,R),       __fmul_rn(-0.418688f,G)), __fmul_rn(-0.081312f,Bl)), 128.0f);
  int c[5];
  c[0] = (int)floorf(__fdiv_rn((float)x, 7.0f));
  c[1] = (int)floorf(__fdiv_rn((float)y, 7.0f));
  c[2] = (int)floorf(__fdiv_rn(Y, 8.0f));
  c[3] = (int)floorf(__fdiv_rn(U, 2.0f));
  c[4] = (int)floorf(__fdiv_rn(V, 2.0f));
  unsigned hh = 0;
  #pragma unroll
  for(int d=0;d<5;d++) hh += (unsigned)c[d]*(unsigned)prime(d);
  hh &= TMASK_;
  hpix[pix]=(int)hh;
  #pragma unroll
  for(int d=0;d<5;d++) cpix[pix*5+d]=(short)c[d];
  atomicMax(&winner[hh], pix);     // last (highest-index) scatter wins, matches XLA/np
  atomicAdd(&m[hh],1.0f);
  float w = conf[pix];
  atomicAdd(&wsplat[hh], w);
  const float* pb = pred + (size_t)b*3*N_;
  atomicAdd(&vb[hh*3+0], __fmul_rn(w, pb[pix]));
  atomicAdd(&vb[hh*3+1], __fmul_rn(w, pb[N_+pix]));
  atomicAdd(&vb[hh*3+2], __fmul_rn(w, pb[2*N_+pix]));
}

// write ctab for occupied slots + wave-aggregated compaction
__global__ __launch_bounds__(256) void k_ctab_compact(const int* winner, const short* cpix, short* ctab,
                                                      int* cidx, int* slot_of, int* count){
  int t = blockIdx.x*256 + threadIdx.x;     // grid exactly T/256
  int wi = winner[t];
  bool occ = (wi>=0);
  if(occ){
    #pragma unroll
    for(int d=0;d<5;d++) ctab[t*5+d]=cpix[wi*5+d];
  }
  unsigned long long mask = __ballot(occ);
  int lane = threadIdx.x & 63;
  int nOcc = __popcll(mask);
  int base = 0;
  if(lane==0 && nOcc) base = atomicAdd(count, nOcc);
  base = __shfl(base, 0, 64);
  if(occ){
    int i = base + __popcll(mask & ((1ull<<lane)-1ull));
    slot_of[i]=t;
    cidx[t]=i;
  }
}

// per compact slot: neighbor compact indices + gather splat data into compact arrays
__global__ __launch_bounds__(256) void k_nbr(const int* count, const int* slot_of, const int* winner,
                      const short* ctab, const int* cidx, const float* m, const float* ws,
                      const float* vb, int* nbr, float* mc, float* wsc, float* vbc, float* n0){
  int i = blockIdx.x*256 + threadIdx.x;     // grid GM_
  int M = *count;
  if(i>=M) return;
  int t = slot_of[i];
  int c[5];
  #pragma unroll
  for(int d=0;d<5;d++) c[d]=(int)ctab[t*5+d];
  #pragma unroll
  for(int j=0;j<10;j++){
    int d=j>>1; int off=(j&1)?1:-1;
    unsigned nh = ((unsigned)t + (unsigned)(off*prime(d))) & TMASK_;
    int nb = -1;
    if(winner[nh]>=0){
      bool eq=true;
      #pragma unroll
      for(int k2=0;k2<5;k2++){
        int expect = c[k2] + ((k2==d)?off:0);
        eq = eq && ((int)ctab[nh*5+k2]==expect);
      }
      if(eq) nb = cidx[nh];
    }
    nbr[i*10+j]=nb;
  }
  mc[i]=m[t]; wsc[i]=ws[t];
  vbc[3*i]=vb[3*t]; vbc[3*i+1]=vb[3*t+1]; vbc[3*i+2]=vb[3*t+2];
  n0[i]=1.0f;
}

__global__ __launch_bounds__(256) void k_bisto(const int* count, const int* nbr,
                                               const float* ns, float* nd, const float* mc){
  int i = blockIdx.x*256 + threadIdx.x;
  int M = *count;
  if(i>=M) return;
  float nv = ns[i];
  float bv = 10.f*nv;
  #pragma unroll
  for(int j=0;j<10;j++){
    int nb = nbr[i*10+j];
    if(nb>=0) bv += ns[nb];
  }
  nd[i] = sqrtf(nv*mc[i]/(bv+1e-12f));
}

// m_final = n*blur(n);  Minv = 1/max(LAM*(m-10n^2)+ws, 1e-5)
__global__ __launch_bounds__(256) void k_mf(const int* count, const int* nbr, const float* n,
                                            const float* mc, const float* wsc, float* mfin, float* minv){
  int i = blockIdx.x*256 + threadIdx.x;
  int M = *count;
  if(i>=M) return;
  float nv = n[i];
  float bv = 10.f*nv;
  #pragma unroll
  for(int j=0;j<10;j++){
    int nb = nbr[i*10+j];
    if(nb>=0) bv += n[nb];
  }
  float mn = nv*bv;
  mfin[i]=mn;
  float Ad = fmaxf(200.0f*(mn - 10.f*nv*nv) + wsc[i], 1e-5f);
  minv[i] = 1.0f/Ad;
  (void)mc;
}

// fused: x0 = b/(ws+eps); Ap=A(x0) with x0 of neighbors recomputed on the fly;
// r=b-Ap; z=Minv r; p=z; rz0 reduction
__global__ __launch_bounds__(256) void k_Ar0(const int* count, const int* nbr, const float* n,
                      const float* mfin, const float* wsc, const float* vbc, const float* minv,
                      float* vx, float* vr, float* vz, float* vp, double* rz0){
  int i = blockIdx.x*256 + threadIdx.x;
  int M = *count;
  double a0=0.0,a1=0.0,a2=0.0;
  if(i<M){
    float wsi = wsc[i];
    float x0 = vbc[3*i]  /(wsi+1e-12f);
    float x1 = vbc[3*i+1]/(wsi+1e-12f);
    float x2 = vbc[3*i+2]/(wsi+1e-12f);
    float nv = n[i];
    float s0=10.f*(nv*x0), s1=10.f*(nv*x1), s2=10.f*(nv*x2);
    #pragma unroll
    for(int j=0;j<10;j++){
      int nb = nbr[i*10+j];
      if(nb>=0){
        float wsn = wsc[nb]; float nn = n[nb];
        s0 += nn*(vbc[3*nb]  /(wsn+1e-12f));
        s1 += nn*(vbc[3*nb+1]/(wsn+1e-12f));
        s2 += nn*(vbc[3*nb+2]/(wsn+1e-12f));
      }
    }
    float mm=mfin[i];
    float A0 = 200.f*(mm*x0 - nv*s0) + wsi*x0;
    float A1 = 200.f*(mm*x1 - nv*s1) + wsi*x1;
    float A2 = 200.f*(mm*x2 - nv*s2) + wsi*x2;
    float r0v = vbc[3*i]  -A0;
    float r1v = vbc[3*i+1]-A1;
    float r2v = vbc[3*i+2]-A2;
    float mi = minv[i];
    float z0=mi*r0v, z1=mi*r1v, z2=mi*r2v;
    vx[3*i]=x0; vx[3*i+1]=x1; vx[3*i+2]=x2;
    vr[3*i]=r0v; vr[3*i+1]=r1v; vr[3*i+2]=r2v;
    vz[3*i]=z0; vz[3*i+1]=z1; vz[3*i+2]=z2;
    vp[3*i]=z0; vp[3*i+1]=z1; vp[3*i+2]=z2;
    a0=(double)r0v*z0; a1=(double)r1v*z1; a2=(double)r2v*z2;
  }
  a0=blockReduceD(a0); a1=blockReduceD(a1); a2=blockReduceD(a2);
  if(threadIdx.x==0){
    atomicAdd(&rz0[0],a0); atomicAdd(&rz0[CH_],a1); atomicAdd(&rz0[2*CH_],a2);
  }
}

// fused upd2 + A: pNew = z + beta*pOld (self and neighbors on the fly, double-buffered);
// Ap = A(pNew); p.Ap reduction
__global__ __launch_bounds__(256) void k_Ap(const int* count, const int* nbr, const float* n,
                     const float* mfin, const float* wsc, const float* z, const float* pOld,
                     float* pNew, float* Ap, const double* bNum, const double* bDen, double* pAp){
  int i = blockIdx.x*256 + threadIdx.x;
  int M = *count;
  double a0=0.0,a1=0.0,a2=0.0;
  float be0=(float)bNum[0]     /((float)bDen[0]     +1e-12f);
  float be1=(float)bNum[CH_]   /((float)bDen[CH_]   +1e-12f);
  float be2=(float)bNum[2*CH_] /((float)bDen[2*CH_] +1e-12f);
  if(i<M){
    float p0 = z[3*i]  +be0*pOld[3*i];
    float p1 = z[3*i+1]+be1*pOld[3*i+1];
    float p2 = z[3*i+2]+be2*pOld[3*i+2];
    float nv = n[i];
    float s0=10.f*(nv*p0), s1=10.f*(nv*p1), s2=10.f*(nv*p2);
    #pragma unroll
    for(int j=0;j<10;j++){
      int nb = nbr[i*10+j];
      if(nb>=0){
        float nn = n[nb];
        s0 += nn*(z[3*nb]  +be0*pOld[3*nb]);
        s1 += nn*(z[3*nb+1]+be1*pOld[3*nb+1]);
        s2 += nn*(z[3*nb+2]+be2*pOld[3*nb+2]);
      }
    }
    float mm=mfin[i], wsi=wsc[i];
    float A0 = 200.f*(mm*p0 - nv*s0) + wsi*p0;
    float A1 = 200.f*(mm*p1 - nv*s1) + wsi*p1;
    float A2 = 200.f*(mm*p2 - nv*s2) + wsi*p2;
    pNew[3*i]=p0; pNew[3*i+1]=p1; pNew[3*i+2]=p2;
    Ap[3*i]=A0; Ap[3*i+1]=A1; Ap[3*i+2]=A2;
    a0=(double)p0*A0; a1=(double)p1*A1; a2=(double)p2*A2;
  }
  a0=blockReduceD(a0); a1=blockReduceD(a1); a2=blockReduceD(a2);
  if(threadIdx.x==0){
    atomicAdd(&pAp[0],a0); atomicAdd(&pAp[CH_],a1); atomicAdd(&pAp[2*CH_],a2);
  }
}

__global__ __launch_bounds__(256) void k_upd1(const int* count, float* x, float* r, float* z,
                       const float* p, const float* Ap, const float* minv,
                       const double* rzCur, const double* pAp, double* rzNew){
  int i = blockIdx.x*256 + threadIdx.x;
  int M = *count;
  double a0=0.0,a1=0.0,a2=0.0;
  float al0=(float)rzCur[0]     /((float)pAp[0]     +1e-12f);
  float al1=(float)rzCur[CH_]   /((float)pAp[CH_]   +1e-12f);
  float al2=(float)rzCur[2*CH_] /((float)pAp[2*CH_] +1e-12f);
  if(i<M){
    float mi = minv[i];
    float x0=x[3*i]  +al0*p[3*i];
    float x1=x[3*i+1]+al1*p[3*i+1];
    float x2=x[3*i+2]+al2*p[3*i+2];
    float r0v=r[3*i]  -al0*Ap[3*i];
    float r1v=r[3*i+1]-al1*Ap[3*i+1];
    float r2v=r[3*i+2]-al2*Ap[3*i+2];
    float z0=mi*r0v, z1=mi*r1v, z2=mi*r2v;
    x[3*i]=x0; x[3*i+1]=x1; x[3*i+2]=x2;
    r[3*i]=r0v; r[3*i+1]=r1v; r[3*i+2]=r2v;
    z[3*i]=z0; z[3*i+1]=z1; z[3*i+2]=z2;
    a0=(double)r0v*z0; a1=(double)r1v*z1; a2=(double)r2v*z2;
  }
  a0=blockReduceD(a0); a1=blockReduceD(a1); a2=blockReduceD(a2);
  if(threadIdx.x==0){
    atomicAdd(&rzNew[0],a0); atomicAdd(&rzNew[CH_],a1); atomicAdd(&rzNew[2*CH_],a2);
  }
}

__global__ __launch_bounds__(256) void k_out(const float* vx, const int* cidx, const int* hpix,
                                             float* out, int b){
  int pix = blockIdx.x*256 + threadIdx.x;   // grid exactly N/256
  int i = cidx[hpix[pix]];
  out[((size_t)(b*3+0))*N_+pix] = vx[3*i];
  out[((size_t)(b*3+1))*N_+pix] = vx[3*i+1];
  out[((size_t)(b*3+2))*N_+pix] = vx[3*i+2];
}

// ---------------- host launcher ----------------

extern "C" void kernel_launch(void* const* d_in, const int* in_sizes, int n_in,
                              void* d_out, int out_size, void* d_ws, size_t ws_size,
                              hipStream_t stream){
  const float* image=(const float*)d_in[0];
  const float* feature=(const float*)d_in[1];
  const float* pred=(const float*)d_in[2];
  const float* w1=(const float*)d_in[3];  const float* b1=(const float*)d_in[4];
  const float* g1=(const float*)d_in[5];  const float* be1=(const float*)d_in[6];
  const float* w2=(const float*)d_in[7];  const float* b2=(const float*)d_in[8];
  const float* g2=(const float*)d_in[9];  const float* be2=(const float*)d_in[10];
  const float* wd1=(const float*)d_in[11];const float* bd1=(const float*)d_in[12];
  const float* gd1=(const float*)d_in[13];const float* bed1=(const float*)d_in[14];
  const float* wd2=(const float*)d_in[15];const float* bd2=(const float*)d_in[16];
  const float* gd2=(const float*)d_in[17];const float* bed2=(const float*)d_in[18];
  const float* wf=(const float*)d_in[19]; const float* bf=(const float*)d_in[20];
  float* outp=(float*)d_out;                          // (B,3,H,W)
  float* confout = outp + (size_t)B_*3*N_;            // (B,1,H,W)

  char* wsb=(char*)d_ws;
  float* scal=(float*)wsb;                  // [0..1] imgmax, [2..3] featmax, [4] confmax
  int* count=(int*)(wsb+256);
  double* scalD=(double*)(wsb+4096);        // padded accumulators, see layout below
  // scalD layout (doubles): [0] zero-vec3 (ch stride 16)
  //   rzArr[it]  at 64 + it*48   (it=0..12)
  //   pApArr[it] at 768 + it*48  (it=0..11)
  //   GN acc     at 2048 + layer*128 + bg*32 (+0 sum, +16 sumsq)
  double* zeroD = scalD;
  auto rzArr  = [&](int it)->double*{ return scalD + 64  + it*48; };
  auto pApArr = [&](int it)->double*{ return scalD + 768 + it*48; };
  auto gnAcc  = [&](int L)->double*{ return scalD + 2048 + L*128; };

  size_t off = 4096 + 65536;
  auto alloc=[&](size_t bytes)->char*{ char* pp=wsb+off; off=(off+bytes+255)&~(size_t)255; return pp; };
  const size_t ALLOC0 = off;

  // CNN region (dead once conf is in d_out; bilateral region overlaps it)
  float* inp  =(float*)alloc((size_t)B_*6*N_*4);
  float* x1   =(float*)alloc((size_t)B_*16*192*256*4);
  float* x2   =(float*)alloc((size_t)B_*16*96*128*4);
  float* dx1  =(float*)alloc((size_t)B_*16*96*128*4);
  float* dx1r =(float*)alloc((size_t)B_*16*192*256*4);
  float* dx2  =(float*)alloc((size_t)B_*16*192*256*4);
  float* dx2r =(float*)alloc((size_t)B_*16*N_*4);
  float* confr=(float*)alloc((size_t)B_*N_*4);

  // bilateral region (reset offset: CNN buffers dead by then)
  off = ALLOC0;
  int*   hpix   =(int*)  alloc((size_t)N_*4);
  short* cpix   =(short*)alloc((size_t)N_*5*2);
  int*   winner =(int*)  alloc((size_t)T_*4);
  short* ctab   =(short*)alloc((size_t)T_*5*2);
  int*   cidx   =(int*)  alloc((size_t)T_*4);
  int*   slot_of=(int*)  alloc((size_t)N_*4);
  float* m      =(float*)alloc((size_t)T_*4);
  float* wsplat =(float*)alloc((size_t)T_*4);
  float* vb     =(float*)alloc((size_t)T_*3*4);
  int*   nbr    =(int*)  alloc((size_t)N_*10*4);
  float* mc     =(float*)alloc((size_t)N_*4);
  float* wsc    =(float*)alloc((size_t)N_*4);
  float* nA     =(float*)alloc((size_t)N_*4);
  float* nB     =(float*)alloc((size_t)N_*4);
  float* mfin   =(float*)alloc((size_t)N_*4);
  float* minv   =(float*)alloc((size_t)N_*4);
  float* vbc    =(float*)alloc((size_t)N_*3*4);
  float* vx     =(float*)alloc((size_t)N_*3*4);
  float* vr     =(float*)alloc((size_t)N_*3*4);
  float* vz     =(float*)alloc((size_t)N_*3*4);
  float* vpA    =(float*)alloc((size_t)N_*3*4);
  float* vpB    =(float*)alloc((size_t)N_*3*4);
  float* vAp    =(float*)alloc((size_t)N_*3*4);

  dim3 blk(256);

  // ---- CNN ----
  k_zero_scal<<<1,blk,0,stream>>>(scal,count,scalD);
  k_maxes<<<(B_*3*N_)/256,blk,0,stream>>>(image,feature,scal);
  k_prep<<<(B_*6*N_)/256,blk,0,stream>>>(image,pred,scal,inp);

  k_conv<<<(B_*16*192*256)/256,blk,0,stream>>>(inp,nullptr,6, w1,b1,x1, 6,H_,W_, 16,192,256, 4,2,1);
  k_gnpartial<<<(B_*16*192*256)/256,blk,0,stream>>>(x1, gnAcc(0), 192*256);
  k_gnapply<<<(B_*16*192*256)/256,blk,0,stream>>>(x1, gnAcc(0), g1, be1, 192*256);

  k_conv<<<(B_*16*96*128)/256,blk,0,stream>>>(x1,nullptr,16, w2,b2,x2, 16,192,256, 16,96,128, 4,2,1);
  k_gnpartial<<<(B_*16*96*128)/256,blk,0,stream>>>(x2, gnAcc(1), 96*128);
  k_gnapply<<<(B_*16*96*128)/256,blk,0,stream>>>(x2, gnAcc(1), g2, be2, 96*128);

  k_conv<<<(B_*16*96*128)/256,blk,0,stream>>>(x2,nullptr,16, wd1,bd1,dx1, 16,96,128, 16,96,128, 3,1,0);
  k_gnpartial<<<(B_*16*96*128)/256,blk,0,stream>>>(dx1, gnAcc(2), 96*128);
  k_gnapply<<<(B_*16*96*128)/256,blk,0,stream>>>(dx1, gnAcc(2), gd1, bed1, 96*128);

  k_resize<<<(B_*16*192*256)/256,blk,0,stream>>>(dx1, dx1r, 16, 96,128, 192,256);

  k_conv<<<(B_*16*192*256)/256,blk,0,stream>>>(dx1r, x1, 16, wd2,bd2,dx2, 32,192,256, 16,192,256, 3,1,0);
  k_gnpartial<<<(B_*16*192*256)/256,blk,0,stream>>>(dx2, gnAcc(3), 192*256);
  k_gnapply<<<(B_*16*192*256)/256,blk,0,stream>>>(dx2, gnAcc(3), gd2, bed2, 192*256);

  k_resize<<<(B_*16*N_)/256,blk,0,stream>>>(dx2, dx2r, 16, 192,256, 384,512);

  k_conv5<<<(B_*N_)/256,blk,0,stream>>>(dx2r, wf, bf, confr, scal);
  k_confnorm<<<(B_*N_)/256,blk,0,stream>>>(confr, scal, confout);

  // ---- bilateral solver per batch ----
  for(int b=0;b<B_;b++){
    const float* confb = confout + (size_t)b*N_;
    k_initslots<<<GT_,blk,0,stream>>>(winner,m,wsplat,vb,scalD,count);
    k_pixel<<<GM_,blk,0,stream>>>(feature,pred,confb,scal,b,hpix,cpix,winner,m,wsplat,vb);
    k_ctab_compact<<<GT_,blk,0,stream>>>(winner,cpix,ctab,cidx,slot_of,count);
    k_nbr<<<GM_,blk,0,stream>>>(count,slot_of,winner,ctab,cidx,m,wsplat,vb,nbr,mc,wsc,vbc,nA);

    float* nbuf[2]={nA,nB};
    for(int it=0; it<10; ++it)
      k_bisto<<<GM_,blk,0,stream>>>(count,nbr,nbuf[it&1],nbuf[(it+1)&1],mc);
    float* nfin = nA;   // 10 iterations -> ends in nA

    k_mf<<<GM_,blk,0,stream>>>(count,nbr,nfin,mc,wsc,mfin,minv);
    k_Ar0<<<GM_,blk,0,stream>>>(count,nbr,nfin,mfin,wsc,vbc,minv,vx,vr,vz,vpA,rzArr(0));

    float* pbuf[2]={vpA,vpB};
    for(int it=0; it<12; ++it){
      const double* bN = (it==0) ? zeroD : rzArr(it);
      const double* bD = (it==0) ? zeroD : rzArr(it-1);
      k_Ap<<<GM_,blk,0,stream>>>(count,nbr,nfin,mfin,wsc,vz,pbuf[it&1],pbuf[(it+1)&1],vAp,bN,bD,pApArr(it));
      k_upd1<<<GM_,blk,0,stream>>>(count,vx,vr,vz,pbuf[(it+1)&1],vAp,minv,rzArr(it),pApArr(it),rzArr(it+1));
    }
    k_out<<<GM_,blk,0,stream>>>(vx,cidx,hpix,outp,b);
  }
  (void)in_sizes; (void)n_in; (void)out_size; (void)ws_size;
}

// Round 3
// 1791.193 us; speedup vs baseline: 5.0494x; 1.2295x over previous
//
#include <hip/hip_runtime.h>

#define H_ 384
#define W_ 512
#define N_ (H_*W_)        // 196608
#define B_ 2
#define T_ 1048576
#define TMASK_ 0xFFFFFu
#define GT_ (T_/256)      // 4096
#define GM_ (N_/256)      // 768
#define CH_ 16            // channel stride (doubles) for padded accumulators (128B)

__device__ __forceinline__ int prime(int d){
  switch(d){
    case 0: return 73856093;
    case 1: return 19349663;
    case 2: return 83492791;
    case 3: return 49979687;
    default: return 24036583;
  }
}

__device__ __forceinline__ float clampScale(float s){ return fminf(fmaxf(s,1e-5f),1.0f); }

__device__ __forceinline__ double blockReduceD(double v){
  __shared__ double sh[4];
  for(int s=32;s>0;s>>=1) v += __shfl_down(v,s,64);
  int lane=threadIdx.x&63, w=threadIdx.x>>6;
  if(lane==0) sh[w]=v;
  __syncthreads();
  double r = sh[0]+sh[1]+sh[2]+sh[3];
  __syncthreads();
  return r;
}
__device__ __forceinline__ float blockReduceMaxF(float v){
  __shared__ float sh[4];
  for(int s=32;s>0;s>>=1) v = fmaxf(v,__shfl_down(v,s,64));
  int lane=threadIdx.x&63, w=threadIdx.x>>6;
  if(lane==0) sh[w]=v;
  __syncthreads();
  float r = fmaxf(fmaxf(sh[0],sh[1]),fmaxf(sh[2],sh[3]));
  __syncthreads();
  return r;
}

// ---------------- CNN kernels ----------------

__global__ __launch_bounds__(256) void k_zero_scal(float* scal, int* count, double* scalD){
  int tid=threadIdx.x;
  if(tid<64) scal[tid]=0.f;
  if(tid==0) *count=0;
  scalD[2048+tid]=0.0;        // GN accumulators (512 doubles)
  scalD[2048+256+tid]=0.0;
}

__global__ __launch_bounds__(256) void k_maxes(const float* img, const float* feat, float* scal){
  int idx = blockIdx.x*256 + threadIdx.x;      // grid exactly B*3*N/256
  int b = idx / (3*N_);
  float mi = blockReduceMaxF(img[idx]);
  float mf = blockReduceMaxF(feat[idx]);
  if(threadIdx.x==0){
    atomicMax((int*)&scal[b],   __float_as_int(mi));
    atomicMax((int*)&scal[2+b], __float_as_int(mf));
  }
}

__global__ __launch_bounds__(256) void k_prep(const float* img, const float* pred, const float* scal, float* inp){
  int idx = blockIdx.x*256 + threadIdx.x;      // grid exactly B*6*N/256
  int pix = idx % N_; int c = (idx/N_)%6; int b = idx/(6*N_);
  float v;
  if(c<3){ float s=clampScale(scal[b]); v = img[((size_t)b*3+c)*N_+pix]/s; }
  else    { v = pred[((size_t)b*3+(c-3))*N_+pix]; }
  inp[idx]=v;
}

// accumulate NCH channels starting at global channel icBase from `plane0`
template<int NCH,int IC,int K,int S,bool EDGE,int IH,int IW>
__device__ __forceinline__ void conv_accum(const float* __restrict__ plane0, int icBase,
                                           int oy, int ox, const float* wlds, float acc[16]){
  for(int ic=0; ic<NCH; ic++){          // rolled (I-cache friendly)
    const float* plane = plane0 + (size_t)ic*IH*IW;
    #pragma unroll
    for(int ky=0;ky<K;ky++){
      int iy = oy*S + ky - 1;
      int cy = min(max(iy,0),IH-1);
      bool yin = (iy>=0)&&(iy<IH);
      const float* row = plane + cy*IW;
      #pragma unroll
      for(int kx=0;kx<K;kx++){
        int ix = ox*S + kx - 1;
        float v;
        if(EDGE){
          int cx = min(max(ix,0),IW-1);
          v = row[cx];
        } else {
          v = (yin && ix>=0 && ix<IW) ? row[ix] : 0.f;
        }
        const float4* wp = (const float4*)&wlds[(((icBase+ic)*K+ky)*K+kx)*16];
        #pragma unroll
        for(int q=0;q<4;q++){
          float4 w4 = wp[q];
          acc[4*q+0] += v*w4.x;
          acc[4*q+1] += v*w4.y;
          acc[4*q+2] += v*w4.z;
          acc[4*q+3] += v*w4.w;
        }
      }
    }
  }
}

// conv with OC=16; each thread: one output pixel, all 16 oc. Weights transposed into LDS.
template<int ICA,int ICB,int K,int S,bool EDGE,int IH,int IW,int OH,int OW>
__global__ __launch_bounds__(256) void k_convT(const float* __restrict__ inA, const float* __restrict__ inB,
                        const float* __restrict__ wt, const float* __restrict__ bias,
                        float* __restrict__ out){
  constexpr int IC = ICA+ICB;
  __shared__ float wlds[IC*K*K*16];
  for(int i=threadIdx.x; i<IC*K*K*16; i+=256){
    int oc=i&15, ickk=i>>4;
    wlds[i] = wt[oc*IC*K*K + ickk];
  }
  __syncthreads();
  int idx = blockIdx.x*256+threadIdx.x;      // grid exactly B*OH*OW/256
  int ox = idx % OW; int t=idx/OW; int oy=t%OH; int b=t/OH;
  float acc[16];
  #pragma unroll
  for(int oc=0;oc<16;oc++) acc[oc]=0.f;
  conv_accum<ICA,IC,K,S,EDGE,IH,IW>(inA + (size_t)b*ICA*IH*IW, 0, oy, ox, wlds, acc);
  if(ICB>0)
    conv_accum<(ICB>0?ICB:1),IC,K,S,EDGE,IH,IW>(inB + (size_t)b*ICB*IH*IW, ICA, oy, ox, wlds, acc);
  #pragma unroll
  for(int oc=0;oc<16;oc++)
    out[(((size_t)b*16+oc)*OH+oy)*OW+ox] = acc[oc] + bias[oc];
}

// grid-wide GN partial sums: acc layout acc[bg*32 + 0]=sum, acc[bg*32+16]=sumsq
__global__ __launch_bounds__(256) void k_gnpartial(const float* x, double* acc, int HW){
  int idx = blockIdx.x*256 + threadIdx.x;      // grid exactly B*16*HW/256
  int c = (idx/HW)%16; int b = idx/(16*HW);
  int bg = b*2 + (c>>3);
  float v = x[idx];
  double s  = blockReduceD((double)v);
  double s2 = blockReduceD((double)v*(double)v);
  if(threadIdx.x==0){
    atomicAdd(&acc[bg*32],    s);
    atomicAdd(&acc[bg*32+16], s2);
  }
}

__global__ __launch_bounds__(256) void k_gnapply(float* x, const double* acc, const float* gamma, const float* beta, int HW){
  int idx = blockIdx.x*256 + threadIdx.x;      // grid exactly B*16*HW/256
  int c = (idx/HW)%16; int b = idx/(16*HW);
  int bg = b*2 + (c>>3);
  double len = 8.0*(double)HW;
  double s = acc[bg*32], s2 = acc[bg*32+16];
  double mean = s/len;
  double var = s2/len - mean*mean;
  float rstd = (float)(1.0/sqrt(var + 1e-5));
  float mf = (float)mean;
  float v = (x[idx]-mf)*rstd*gamma[c]+beta[c];
  x[idx] = fmaxf(v,0.f);
}

__global__ __launch_bounds__(256) void k_resize(const float* in, float* out, int C, int IH, int IW, int OH, int OW){
  int idx = blockIdx.x*256 + threadIdx.x;
  int total = B_*C*OH*OW;
  if(idx>=total) return;
  int ox = idx%OW; int t=idx/OW; int oy=t%OH; t/=OH;   // t = b*C+c
  const float* plane = in + (size_t)t*IH*IW;
  float sy = (float)IH/(float)OH, sx=(float)IW/(float)OW;
  float fy = (oy+0.5f)*sy-0.5f, fx=(ox+0.5f)*sx-0.5f;
  float fy0 = floorf(fy), fx0=floorf(fx);
  float ty = fy-fy0, tx = fx-fx0;
  int y0 = min(max((int)fy0,0),IH-1), y1 = min(max((int)fy0+1,0),IH-1);
  int x0 = min(max((int)fx0,0),IW-1), x1 = min(max((int)fx0+1,0),IW-1);
  float v00=plane[y0*IW+x0], v01=plane[y0*IW+x1], v10=plane[y1*IW+x0], v11=plane[y1*IW+x1];
  out[idx] = (1.f-ty)*((1.f-tx)*v00+tx*v01) + ty*((1.f-tx)*v10+tx*v11);
}

__global__ __launch_bounds__(256) void k_conv5(const float* in, const float* wf, const float* bf,
                                               float* confr, float* scal){
  int idx = blockIdx.x*256 + threadIdx.x;   // grid exactly B*N/256
  int pix = idx % N_; int b = idx / N_;
  int oy = pix / W_, ox = pix % W_;
  float acc = bf[0];
  for(int ic=0; ic<16; ic++){
    const float* plane = in + ((size_t)b*16+ic)*N_;
    #pragma unroll
    for(int ky=0;ky<3;ky++){
      int iy = min(max(oy+ky-1,0),H_-1);
      const float* row = plane + iy*W_;
      #pragma unroll
      for(int kx=0;kx<3;kx++){
        int ix = min(max(ox+kx-1,0),W_-1);
        acc += row[ix]*wf[(ic*3+ky)*3+kx];
      }
    }
  }
  float c = 0.5f*(tanhf(acc)+1.0f);
  confr[idx]=c;
  float mx = blockReduceMaxF(c);
  if(threadIdx.x==0) atomicMax((int*)&scal[4], __float_as_int(mx));
}

__global__ __launch_bounds__(256) void k_confnorm(const float* confr, const float* scal, float* confout){
  int idx = blockIdx.x*256 + threadIdx.x;   // grid exactly B*N/256
  confout[idx] = confr[idx] / fmaxf(scal[4], 1e-5f);
}

// ---------------- bilateral solver kernels ----------------

__global__ __launch_bounds__(256) void k_initslots(int* winner, float* m, float* wsplat,
                                                   float* vb, double* scalD, int* count){
  int t = blockIdx.x*256 + threadIdx.x;     // grid exactly T/256
  winner[t]=-1; m[t]=0.f; wsplat[t]=0.f;
  vb[3*t]=0.f; vb[3*t+1]=0.f; vb[3*t+2]=0.f;
  if(t<2048) scalD[t]=0.0;                  // CG scalar accumulators
  if(t==0) *count=0;
}

__global__ __launch_bounds__(256) void k_pixel(const float* feat, const float* pred, const float* conf,
                        const float* scal, int b, int* hpix, short* cpix, int* winner,
                        float* m, float* wsplat, float* vb){
  int pix = blockIdx.x*256 + threadIdx.x;   // grid exactly N/256
  int y = pix / W_, x = pix % W_;
  float sF = clampScale(scal[2+b]);
  const float* fb = feat + (size_t)b*3*N_;
  // exact reference eval order, no FMA contraction (coords are integer-binned)
  float R  = __fmul_rn(__fdiv_rn(fb[pix],      sF), 255.0f);
  float G  = __fmul_rn(__fdiv_rn(fb[N_+pix],   sF), 255.0f);
  float Bl = __fmul_rn(__fdiv_rn(fb[2*N_+pix], sF), 255.0f);
  float Y = __fadd_rn(__fadd_rn(__fadd_rn(__fmul_rn(0.299f,R),     __fmul_rn(0.587f,G)),  __fmul_rn(0.114f,Bl)), 0.0f);
  float U = __fadd_rn(__fadd_rn(__fadd_rn(__fmul_rn(-0.168736f,R), __fmul_rn(-0.331264f,G)), __fmul_rn(0.5f,Bl)), 128.0f);
  float V = __fadd_rn(__fadd_rn(__fadd_rn(__fmul_rn(0.5f,R),       __fmul_rn(-0.418688f,G)), __fmul_rn(-0.081312f,Bl)), 128.0f);
  int c[5];
  c[0] = (int)floorf(__fdiv_rn((float)x, 7.0f));
  c[1] = (int)floorf(__fdiv_rn((float)y, 7.0f));
  c[2] = (int)floorf(__fdiv_rn(Y, 8.0f));
  c[3] = (int)floorf(__fdiv_rn(U, 2.0f));
  c[4] = (int)floorf(__fdiv_rn(V, 2.0f));
  unsigned hh = 0;
  #pragma unroll
  for(int d=0;d<5;d++) hh += (unsigned)c[d]*(unsigned)prime(d);
  hh &= TMASK_;
  hpix[pix]=(int)hh;
  #pragma unroll
  for(int d=0;d<5;d++) cpix[pix*5+d]=(short)c[d];
  atomicMax(&winner[hh], pix);     // last (highest-index) scatter wins, matches XLA/np
  atomicAdd(&m[hh],1.0f);
  float w = conf[pix];
  atomicAdd(&wsplat[hh], w);
  const float* pb = pred + (size_t)b*3*N_;
  atomicAdd(&vb[hh*3+0], __fmul_rn(w, pb[pix]));
  atomicAdd(&vb[hh*3+1], __fmul_rn(w, pb[N_+pix]));
  atomicAdd(&vb[hh*3+2], __fmul_rn(w, pb[2*N_+pix]));
}

// write ctab for occupied slots + wave-aggregated compaction
__global__ __launch_bounds__(256) void k_ctab_compact(const int* winner, const short* cpix, short* ctab,
                                                      int* cidx, int* slot_of, int* count){
  int t = blockIdx.x*256 + threadIdx.x;     // grid exactly T/256
  int wi = winner[t];
  bool occ = (wi>=0);
  if(occ){
    #pragma unroll
    for(int d=0;d<5;d++) ctab[t*5+d]=cpix[wi*5+d];
  }
  unsigned long long mask = __ballot(occ);
  int lane = threadIdx.x & 63;
  int nOcc = __popcll(mask);
  int base = 0;
  if(lane==0 && nOcc) base = atomicAdd(count, nOcc);
  base = __shfl(base, 0, 64);
  if(occ){
    int i = base + __popcll(mask & ((1ull<<lane)-1ull));
    slot_of[i]=t;
    cidx[t]=i;
  }
}

// per compact slot: neighbor compact indices (padded to 12) + gather splat data into compact arrays
__global__ __launch_bounds__(256) void k_nbr(const int* count, const int* slot_of, const int* winner,
                      const short* ctab, const int* cidx, const float* m, const float* ws,
                      const float* vb, int* nbr, float* mc, float4* vbc4, float* n0){
  int i = blockIdx.x*256 + threadIdx.x;     // grid GM_
  int M = *count;
  if(i>=M) return;
  int t = slot_of[i];
  int c[5];
  #pragma unroll
  for(int d=0;d<5;d++) c[d]=(int)ctab[t*5+d];
  #pragma unroll
  for(int j=0;j<10;j++){
    int d=j>>1; int off=(j&1)?1:-1;
    unsigned nh = ((unsigned)t + (unsigned)(off*prime(d))) & TMASK_;
    int nb = -1;
    if(winner[nh]>=0){
      bool eq=true;
      #pragma unroll
      for(int k2=0;k2<5;k2++){
        int expect = c[k2] + ((k2==d)?off:0);
        eq = eq && ((int)ctab[nh*5+k2]==expect);
      }
      if(eq) nb = cidx[nh];
    }
    nbr[i*12+j]=nb;
  }
  nbr[i*12+10]=-1; nbr[i*12+11]=-1;
  mc[i]=m[t];
  float wsv = ws[t];
  vbc4[i] = make_float4(vb[3*t], vb[3*t+1], vb[3*t+2], wsv);
  n0[i]=1.0f;
}

__global__ __launch_bounds__(256) void k_bisto(const int* count, const int* nbr,
                                               const float* ns, float* nd, const float* mc){
  int i = blockIdx.x*256 + threadIdx.x;
  int M = *count;
  if(i>=M) return;
  float nv = ns[i];
  float bv = 10.f*nv;
  #pragma unroll
  for(int j=0;j<10;j++){
    int nb = nbr[i*12+j];
    if(nb>=0) bv += ns[nb];
  }
  nd[i] = sqrtf(nv*mc[i]/(bv+1e-12f));
}

// fused mf + Ar0:
//   mfin = n*blur(n); minv = 1/max(LAM*(mfin-10n^2)+ws,1e-5)
//   x0 = b/(ws+eps); Ap=A(x0) (neighbor x0 recomputed); r=b-Ap; z=minv*r; p=z; rz0 reduce
// stores meta4=(n,mfin,ws,minv), x4, r4=(r,minv), p4=(p,n)
__global__ __launch_bounds__(256) void k_Ar0(const int* count, const int* nbr, const float* n,
                      const float4* vbc4, float4* meta4, float4* x4, float4* r4, float4* p4,
                      double* rz0){
  int i = blockIdx.x*256 + threadIdx.x;
  int M = *count;
  double a0=0.0,a1=0.0,a2=0.0;
  if(i<M){
    float4 vb4 = vbc4[i];
    float wsi = vb4.w;
    float nv = n[i];
    float x0 = vb4.x/(wsi+1e-12f);
    float x1 = vb4.y/(wsi+1e-12f);
    float x2 = vb4.z/(wsi+1e-12f);
    float bv = 10.f*nv;
    float s0=10.f*(nv*x0), s1=10.f*(nv*x1), s2=10.f*(nv*x2);
    #pragma unroll
    for(int j=0;j<10;j++){
      int nb = nbr[i*12+j];
      if(nb>=0){
        float4 vbn = vbc4[nb];
        float nn = n[nb];
        bv += nn;
        s0 += nn*(vbn.x/(vbn.w+1e-12f));
        s1 += nn*(vbn.y/(vbn.w+1e-12f));
        s2 += nn*(vbn.z/(vbn.w+1e-12f));
      }
    }
    float mfin = nv*bv;
    float Ad = fmaxf(200.0f*(mfin - 10.f*nv*nv) + wsi, 1e-5f);
    float mi = 1.0f/Ad;
    float A0 = 200.f*(mfin*x0 - nv*s0) + wsi*x0;
    float A1 = 200.f*(mfin*x1 - nv*s1) + wsi*x1;
    float A2 = 200.f*(mfin*x2 - nv*s2) + wsi*x2;
    float r0v = vb4.x-A0, r1v = vb4.y-A1, r2v = vb4.z-A2;
    float z0=mi*r0v, z1=mi*r1v, z2=mi*r2v;
    meta4[i]=make_float4(nv,mfin,wsi,mi);
    x4[i]=make_float4(x0,x1,x2,0.f);
    r4[i]=make_float4(r0v,r1v,r2v,mi);
    p4[i]=make_float4(z0,z1,z2,nv);
    a0=(double)r0v*z0; a1=(double)r1v*z1; a2=(double)r2v*z2;
  }
  a0=blockReduceD(a0); a1=blockReduceD(a1); a2=blockReduceD(a2);
  if(threadIdx.x==0){
    atomicAdd(&rz0[0],a0); atomicAdd(&rz0[CH_],a1); atomicAdd(&rz0[2*CH_],a2);
  }
}

// fused p-update + A: p = z + beta*pOld with z = r4.w*r4.xyz recomputed (self & neighbors);
// Ap = A(p); p.Ap reduction.  r4=(r,minv), pOld4=(p,n) -> pNew4=(p,n)
__global__ __launch_bounds__(256) void k_Ap(const int* count, const int* nbr, const float4* meta4,
                     const float4* r4, const float4* pOld4, float4* pNew4, float4* Ap4,
                     const double* bNum, const double* bDen, double* pAp){
  int i = blockIdx.x*256 + threadIdx.x;
  int M = *count;
  double a0=0.0,a1=0.0,a2=0.0;
  float be0=(float)bNum[0]     /((float)bDen[0]     +1e-12f);
  float be1=(float)bNum[CH_]   /((float)bDen[CH_]   +1e-12f);
  float be2=(float)bNum[2*CH_] /((float)bDen[2*CH_] +1e-12f);
  if(i<M){
    float4 mt = meta4[i];
    float nv = mt.x, mfin = mt.y, wsi = mt.z;
    float4 rs = r4[i];
    float4 ps = pOld4[i];
    float p0 = rs.w*rs.x + be0*ps.x;
    float p1 = rs.w*rs.y + be1*ps.y;
    float p2 = rs.w*rs.z + be2*ps.z;
    float s0=10.f*(nv*p0), s1=10.f*(nv*p1), s2=10.f*(nv*p2);
    #pragma unroll
    for(int j=0;j<10;j++){
      int nb = nbr[i*12+j];
      if(nb>=0){
        float4 rn = r4[nb];
        float4 pn = pOld4[nb];
        float nn = pn.w;
        s0 += nn*(rn.w*rn.x + be0*pn.x);
        s1 += nn*(rn.w*rn.y + be1*pn.y);
        s2 += nn*(rn.w*rn.z + be2*pn.z);
      }
    }
    float A0 = 200.f*(mfin*p0 - nv*s0) + wsi*p0;
    float A1 = 200.f*(mfin*p1 - nv*s1) + wsi*p1;
    float A2 = 200.f*(mfin*p2 - nv*s2) + wsi*p2;
    pNew4[i]=make_float4(p0,p1,p2,nv);
    Ap4[i]=make_float4(A0,A1,A2,0.f);
    a0=(double)p0*A0; a1=(double)p1*A1; a2=(double)p2*A2;
  }
  a0=blockReduceD(a0); a1=blockReduceD(a1); a2=blockReduceD(a2);
  if(threadIdx.x==0){
    atomicAdd(&pAp[0],a0); atomicAdd(&pAp[CH_],a1); atomicAdd(&pAp[2*CH_],a2);
  }
}

__global__ __launch_bounds__(256) void k_upd1(const int* count, float4* x4, float4* r4,
                       const float4* p4, const float4* Ap4,
                       const double* rzCur, const double* pAp, double* rzNew){
  int i = blockIdx.x*256 + threadIdx.x;
  int M = *count;
  double a0=0.0,a1=0.0,a2=0.0;
  float al0=(float)rzCur[0]     /((float)pAp[0]     +1e-12f);
  float al1=(float)rzCur[CH_]   /((float)pAp[CH_]   +1e-12f);
  float al2=(float)rzCur[2*CH_] /((float)pAp[2*CH_] +1e-12f);
  if(i<M){
    float4 xv = x4[i];
    float4 rv = r4[i];
    float4 pv = p4[i];
    float4 av = Ap4[i];
    float mi = rv.w;
    float x0=xv.x+al0*pv.x, x1=xv.y+al1*pv.y, x2=xv.z+al2*pv.z;
    float r0v=rv.x-al0*av.x, r1v=rv.y-al1*av.y, r2v=rv.z-al2*av.z;
    float z0=mi*r0v, z1=mi*r1v, z2=mi*r2v;
    x4[i]=make_float4(x0,x1,x2,0.f);
    r4[i]=make_float4(r0v,r1v,r2v,mi);
    a0=(double)r0v*z0; a1=(double)r1v*z1; a2=(double)r2v*z2;
  }
  a0=blockReduceD(a0); a1=blockReduceD(a1); a2=blockReduceD(a2);
  if(threadIdx.x==0){
    atomicAdd(&rzNew[0],a0); atomicAdd(&rzNew[CH_],a1); atomicAdd(&rzNew[2*CH_],a2);
  }
}

__global__ __launch_bounds__(256) void k_out(const float4* x4, const int* cidx, const int* hpix,
                                             float* out, int b){
  int pix = blockIdx.x*256 + threadIdx.x;   // grid exactly N/256
  int i = cidx[hpix[pix]];
  float4 xv = x4[i];
  out[((size_t)(b*3+0))*N_+pix] = xv.x;
  out[((size_t)(b*3+1))*N_+pix] = xv.y;
  out[((size_t)(b*3+2))*N_+pix] = xv.z;
}

// ---------------- host launcher ----------------

extern "C" void kernel_launch(void* const* d_in, const int* in_sizes, int n_in,
                              void* d_out, int out_size, void* d_ws, size_t ws_size,
                              hipStream_t stream){
  const float* image=(const float*)d_in[0];
  const float* feature=(const float*)d_in[1];
  const float* pred=(const float*)d_in[2];
  const float* w1=(const float*)d_in[3];  const float* b1=(const float*)d_in[4];
  const float* g1=(const float*)d_in[5];  const float* be1=(const float*)d_in[6];
  const float* w2=(const float*)d_in[7];  const float* b2=(const float*)d_in[8];
  const float* g2=(const float*)d_in[9];  const float* be2=(const float*)d_in[10];
  const float* wd1=(const float*)d_in[11];const float* bd1=(const float*)d_in[12];
  const float* gd1=(const float*)d_in[13];const float* bed1=(const float*)d_in[14];
  const float* wd2=(const float*)d_in[15];const float* bd2=(const float*)d_in[16];
  const float* gd2=(const float*)d_in[17];const float* bed2=(const float*)d_in[18];
  const float* wf=(const float*)d_in[19]; const float* bf=(const float*)d_in[20];
  float* outp=(float*)d_out;                          // (B,3,H,W)
  float* confout = outp + (size_t)B_*3*N_;            // (B,1,H,W)

  char* wsb=(char*)d_ws;
  float* scal=(float*)wsb;                  // [0..1] imgmax, [2..3] featmax, [4] confmax
  int* count=(int*)(wsb+256);
  double* scalD=(double*)(wsb+4096);
  // scalD layout (doubles): [0..47] zero-vec3 (ch stride 16)
  //   rzArr[it]  at 64 + it*48   (it=0..13)
  //   pApArr[it] at 768 + it*48  (it=0..12)
  //   GN acc     at 2048 + layer*128 + bg*32 (+0 sum, +16 sumsq)
  double* zeroD = scalD;
  auto rzArr  = [&](int it)->double*{ return scalD + 64  + it*48; };
  auto pApArr = [&](int it)->double*{ return scalD + 768 + it*48; };
  auto gnAcc  = [&](int L)->double*{ return scalD + 2048 + L*128; };

  size_t off = 4096 + 65536;
  auto alloc=[&](size_t bytes)->char*{ char* pp=wsb+off; off=(off+bytes+255)&~(size_t)255; return pp; };
  const size_t ALLOC0 = off;

  // CNN region (dead once conf is in d_out; bilateral region overlaps it)
  float* inp  =(float*)alloc((size_t)B_*6*N_*4);
  float* x1   =(float*)alloc((size_t)B_*16*192*256*4);
  float* x2   =(float*)alloc((size_t)B_*16*96*128*4);
  float* dx1  =(float*)alloc((size_t)B_*16*96*128*4);
  float* dx1r =(float*)alloc((size_t)B_*16*192*256*4);
  float* dx2  =(float*)alloc((size_t)B_*16*192*256*4);
  float* dx2r =(float*)alloc((size_t)B_*16*N_*4);
  float* confr=(float*)alloc((size_t)B_*N_*4);

  // bilateral region (reset offset: CNN buffers dead by then)
  off = ALLOC0;
  int*    hpix   =(int*)   alloc((size_t)N_*4);
  short*  cpix   =(short*) alloc((size_t)N_*5*2);
  int*    winner =(int*)   alloc((size_t)T_*4);
  short*  ctab   =(short*) alloc((size_t)T_*5*2);
  int*    cidx   =(int*)   alloc((size_t)T_*4);
  int*    slot_of=(int*)   alloc((size_t)N_*4);
  float*  m      =(float*) alloc((size_t)T_*4);
  float*  wsplat =(float*) alloc((size_t)T_*4);
  float*  vb     =(float*) alloc((size_t)T_*3*4);
  int*    nbr    =(int*)   alloc((size_t)N_*12*4);
  float*  mc     =(float*) alloc((size_t)N_*4);
  float*  nA     =(float*) alloc((size_t)N_*4);
  float*  nB     =(float*) alloc((size_t)N_*4);
  float4* vbc4   =(float4*)alloc((size_t)N_*16);
  float4* meta4  =(float4*)alloc((size_t)N_*16);
  float4* x4     =(float4*)alloc((size_t)N_*16);
  float4* r4     =(float4*)alloc((size_t)N_*16);
  float4* pA4    =(float4*)alloc((size_t)N_*16);
  float4* pB4    =(float4*)alloc((size_t)N_*16);
  float4* Ap4    =(float4*)alloc((size_t)N_*16);

  dim3 blk(256);

  // ---- CNN ----
  k_zero_scal<<<1,blk,0,stream>>>(scal,count,scalD);
  k_maxes<<<(B_*3*N_)/256,blk,0,stream>>>(image,feature,scal);
  k_prep<<<(B_*6*N_)/256,blk,0,stream>>>(image,pred,scal,inp);

  k_convT<6,0,4,2,true,384,512,192,256><<<(B_*192*256)/256,blk,0,stream>>>(inp,inp,w1,b1,x1);
  k_gnpartial<<<(B_*16*192*256)/256,blk,0,stream>>>(x1, gnAcc(0), 192*256);
  k_gnapply<<<(B_*16*192*256)/256,blk,0,stream>>>(x1, gnAcc(0), g1, be1, 192*256);

  k_convT<16,0,4,2,true,192,256,96,128><<<(B_*96*128)/256,blk,0,stream>>>(x1,x1,w2,b2,x2);
  k_gnpartial<<<(B_*16*96*128)/256,blk,0,stream>>>(x2, gnAcc(1), 96*128);
  k_gnapply<<<(B_*16*96*128)/256,blk,0,stream>>>(x2, gnAcc(1), g2, be2, 96*128);

  k_convT<16,0,3,1,false,96,128,96,128><<<(B_*96*128)/256,blk,0,stream>>>(x2,x2,wd1,bd1,dx1);
  k_gnpartial<<<(B_*16*96*128)/256,blk,0,stream>>>(dx1, gnAcc(2), 96*128);
  k_gnapply<<<(B_*16*96*128)/256,blk,0,stream>>>(dx1, gnAcc(2), gd1, bed1, 96*128);

  k_resize<<<(B_*16*192*256)/256,blk,0,stream>>>(dx1, dx1r, 16, 96,128, 192,256);

  k_convT<16,16,3,1,false,192,256,192,256><<<(B_*192*256)/256,blk,0,stream>>>(dx1r,x1,wd2,bd2,dx2);
  k_gnpartial<<<(B_*16*192*256)/256,blk,0,stream>>>(dx2, gnAcc(3), 192*256);
  k_gnapply<<<(B_*16*192*256)/256,blk,0,stream>>>(dx2, gnAcc(3), gd2, bed2, 192*256);

  k_resize<<<(B_*16*N_)/256,blk,0,stream>>>(dx2, dx2r, 16, 192,256, 384,512);

  k_conv5<<<(B_*N_)/256,blk,0,stream>>>(dx2r, wf, bf, confr, scal);
  k_confnorm<<<(B_*N_)/256,blk,0,stream>>>(confr, scal, confout);

  // ---- bilateral solver per batch ----
  for(int b=0;b<B_;b++){
    const float* confb = confout + (size_t)b*N_;
    k_initslots<<<GT_,blk,0,stream>>>(winner,m,wsplat,vb,scalD,count);
    k_pixel<<<GM_,blk,0,stream>>>(feature,pred,confb,scal,b,hpix,cpix,winner,m,wsplat,vb);
    k_ctab_compact<<<GT_,blk,0,stream>>>(winner,cpix,ctab,cidx,slot_of,count);
    k_nbr<<<GM_,blk,0,stream>>>(count,slot_of,winner,ctab,cidx,m,wsplat,vb,nbr,mc,vbc4,nA);

    float* nbuf[2]={nA,nB};
    for(int it=0; it<10; ++it)
      k_bisto<<<GM_,blk,0,stream>>>(count,nbr,nbuf[it&1],nbuf[(it+1)&1],mc);
    float* nfin = nA;   // 10 iterations -> ends in nA

    k_Ar0<<<GM_,blk,0,stream>>>(count,nbr,nfin,vbc4,meta4,x4,r4,pA4,rzArr(0));

    float4* pbuf[2]={pA4,pB4};
    for(int it=0; it<12; ++it){
      const double* bN = (it==0) ? zeroD : rzArr(it);
      const double* bD = (it==0) ? zeroD : rzArr(it-1);
      k_Ap<<<GM_,blk,0,stream>>>(count,nbr,meta4,r4,pbuf[it&1],pbuf[(it+1)&1],Ap4,bN,bD,pApArr(it));
      k_upd1<<<GM_,blk,0,stream>>>(count,x4,r4,pbuf[(it+1)&1],Ap4,rzArr(it),pApArr(it),rzArr(it+1));
    }
    k_out<<<GM_,blk,0,stream>>>(x4,cidx,hpix,outp,b);
  }
  (void)in_sizes; (void)n_in; (void)out_size; (void)ws_size;
}

// Round 4
// 1079.664 us; speedup vs baseline: 8.3770x; 1.6590x over previous
//
#include <hip/hip_runtime.h>

#define H_ 384
#define W_ 512
#define N_ (H_*W_)        // 196608
#define B_ 2
#define T_ 1048576
#define TMASK_ 0xFFFFFu
#define G2N_ ((2*N_)/256) // 1536
#define G2T_ ((2*T_)/256) // 8192
#define CH_ 16            // channel stride (doubles) in padded accumulators (128B)
// scalD layout (doubles):
//   [0..47]    zeroD (stays 0; used as beta num/den at it==0)
//   rz  [b][it] at 64   + b*672 + it*48   (it=0..13)
//   pAp [b][it] at 1408 + b*624 + it*48   (it=0..12)
//   GN acc      at 2688 + L*128 + bg*32 (+0 sum, +16 sumsq)
#define RZ0_ 64
#define RZB_ 672
#define PAP0_ 1408
#define PAPB_ 624
#define GN0_ 2688

__device__ __forceinline__ int prime(int d){
  switch(d){
    case 0: return 73856093;
    case 1: return 19349663;
    case 2: return 83492791;
    case 3: return 49979687;
    default: return 24036583;
  }
}

__device__ __forceinline__ float clampScale(float s){ return fminf(fmaxf(s,1e-5f),1.0f); }

__device__ __forceinline__ double blockReduceD(double v){
  __shared__ double sh[4];
  for(int s=32;s>0;s>>=1) v += __shfl_down(v,s,64);
  int lane=threadIdx.x&63, w=threadIdx.x>>6;
  if(lane==0) sh[w]=v;
  __syncthreads();
  double r = sh[0]+sh[1]+sh[2]+sh[3];
  __syncthreads();
  return r;
}
__device__ __forceinline__ float blockReduceMaxF(float v){
  __shared__ float sh[4];
  for(int s=32;s>0;s>>=1) v = fmaxf(v,__shfl_down(v,s,64));
  int lane=threadIdx.x&63, w=threadIdx.x>>6;
  if(lane==0) sh[w]=v;
  __syncthreads();
  float r = fmaxf(fmaxf(sh[0],sh[1]),fmaxf(sh[2],sh[3]));
  __syncthreads();
  return r;
}

// ---------------- init ----------------

__global__ __launch_bounds__(256) void k_init1(float* scal, int* count, double* scalD){
  int t = blockIdx.x*256 + threadIdx.x;   // grid 16 blocks
  if(t<64) scal[t]=0.f;
  if(t<2) count[t]=0;
  if(t<3584) scalD[t]=0.0;
}

// runs AFTER the CNN (bilateral region overlaps CNN scratch)
__global__ __launch_bounds__(256) void k_init2(int* winner, float* mcomp, float4* splat4){
  int t = blockIdx.x*256 + threadIdx.x;   // grid exactly 2T/256
  winner[t]=-1;
  if(t<2*N_){ mcomp[t]=0.f; splat4[t]=make_float4(0.f,0.f,0.f,0.f); }
}

// ---------------- CNN kernels ----------------

__global__ __launch_bounds__(256) void k_maxes(const float* img, const float* feat, float* scal){
  int idx = blockIdx.x*256 + threadIdx.x;      // grid exactly B*3*N/256
  int b = idx / (3*N_);
  float mi = blockReduceMaxF(img[idx]);
  float mf = blockReduceMaxF(feat[idx]);
  if(threadIdx.x==0){
    atomicMax((int*)&scal[b],   __float_as_int(mi));
    atomicMax((int*)&scal[2+b], __float_as_int(mf));
  }
}

__global__ __launch_bounds__(256) void k_prep(const float* img, const float* pred, const float* scal, float* inp){
  int idx = blockIdx.x*256 + threadIdx.x;      // grid exactly B*6*N/256
  int pix = idx % N_; int c = (idx/N_)%6; int b = idx/(6*N_);
  float v;
  if(c<3){ float s=clampScale(scal[b]); v = img[((size_t)b*3+c)*N_+pix]/s; }
  else    { v = pred[((size_t)b*3+(c-3))*N_+pix]; }
  inp[idx]=v;
}

template<int NCH,int IC,int K,int S,bool EDGE,int IH,int IW>
__device__ __forceinline__ void conv_accum(const float* __restrict__ plane0, int icBase,
                                           int oy, int ox, const float* wlds, float acc[16]){
  for(int ic=0; ic<NCH; ic++){
    const float* plane = plane0 + (size_t)ic*IH*IW;
    #pragma unroll
    for(int ky=0;ky<K;ky++){
      int iy = oy*S + ky - 1;
      int cy = min(max(iy,0),IH-1);
      bool yin = (iy>=0)&&(iy<IH);
      const float* row = plane + cy*IW;
      #pragma unroll
      for(int kx=0;kx<K;kx++){
        int ix = ox*S + kx - 1;
        float v;
        if(EDGE){
          int cx = min(max(ix,0),IW-1);
          v = row[cx];
        } else {
          v = (yin && ix>=0 && ix<IW) ? row[ix] : 0.f;
        }
        const float4* wp = (const float4*)&wlds[(((icBase+ic)*K+ky)*K+kx)*16];
        #pragma unroll
        for(int q=0;q<4;q++){
          float4 w4 = wp[q];
          acc[4*q+0] += v*w4.x;
          acc[4*q+1] += v*w4.y;
          acc[4*q+2] += v*w4.z;
          acc[4*q+3] += v*w4.w;
        }
      }
    }
  }
}

// conv OC=16, one thread = one pixel all 16 oc; weights transposed into LDS;
// fused GroupNorm partial sums (groups = oc 0..7 / 8..15) into gnacc.
template<int ICA,int ICB,int K,int S,bool EDGE,int IH,int IW,int OH,int OW>
__global__ __launch_bounds__(256) void k_convT(const float* __restrict__ inA, const float* __restrict__ inB,
                        const float* __restrict__ wt, const float* __restrict__ bias,
                        float* __restrict__ out, double* gnacc){
  constexpr int IC = ICA+ICB;
  __shared__ float wlds[IC*K*K*16];
  __shared__ float blds[16];
  for(int i=threadIdx.x; i<IC*K*K*16; i+=256){
    int oc=i&15, ickk=i>>4;
    wlds[i] = wt[oc*IC*K*K + ickk];
  }
  if(threadIdx.x<16) blds[threadIdx.x]=bias[threadIdx.x];
  __syncthreads();
  int idx = blockIdx.x*256+threadIdx.x;      // grid exactly B*OH*OW/256
  int ox = idx % OW; int t=idx/OW; int oy=t%OH; int b=t/OH;
  float acc[16];
  #pragma unroll
  for(int oc=0;oc<16;oc++) acc[oc]=0.f;
  conv_accum<ICA,IC,K,S,EDGE,IH,IW>(inA + (size_t)b*ICA*IH*IW, 0, oy, ox, wlds, acc);
  if(ICB>0)
    conv_accum<(ICB>0?ICB:1),IC,K,S,EDGE,IH,IW>(inB + (size_t)b*ICB*IH*IW, ICA, oy, ox, wlds, acc);
  double sl=0.0,s2l=0.0,sh=0.0,s2h=0.0;
  #pragma unroll
  for(int oc=0;oc<16;oc++){
    float vv = acc[oc] + blds[oc];
    out[(((size_t)b*16+oc)*OH+oy)*OW+ox] = vv;
    if(oc<8){ sl += vv; s2l += (double)vv*(double)vv; }
    else    { sh += vv; s2h += (double)vv*(double)vv; }
  }
  sl=blockReduceD(sl); s2l=blockReduceD(s2l);
  sh=blockReduceD(sh); s2h=blockReduceD(s2h);
  if(threadIdx.x==0){
    atomicAdd(&gnacc[(b*2+0)*32],    sl);
    atomicAdd(&gnacc[(b*2+0)*32+16], s2l);
    atomicAdd(&gnacc[(b*2+1)*32],    sh);
    atomicAdd(&gnacc[(b*2+1)*32+16], s2h);
  }
}

__global__ __launch_bounds__(256) void k_gnapply(float* x, const double* acc, const float* gamma, const float* beta, int HW){
  int idx = blockIdx.x*256 + threadIdx.x;      // grid exactly B*16*HW/256
  int c = (idx/HW)%16; int b = idx/(16*HW);
  int bg = b*2 + (c>>3);
  double len = 8.0*(double)HW;
  double s = acc[bg*32], s2 = acc[bg*32+16];
  double mean = s/len;
  double var = s2/len - mean*mean;
  float rstd = (float)(1.0/sqrt(var + 1e-5));
  float mf = (float)mean;
  float v = (x[idx]-mf)*rstd*gamma[c]+beta[c];
  x[idx] = fmaxf(v,0.f);
}

__global__ __launch_bounds__(256) void k_resize(const float* in, float* out, int C, int IH, int IW, int OH, int OW){
  int idx = blockIdx.x*256 + threadIdx.x;
  int total = B_*C*OH*OW;
  if(idx>=total) return;
  int ox = idx%OW; int t=idx/OW; int oy=t%OH; t/=OH;   // t = b*C+c
  const float* plane = in + (size_t)t*IH*IW;
  float sy = (float)IH/(float)OH, sx=(float)IW/(float)OW;
  float fy = (oy+0.5f)*sy-0.5f, fx=(ox+0.5f)*sx-0.5f;
  float fy0 = floorf(fy), fx0=floorf(fx);
  float ty = fy-fy0, tx = fx-fx0;
  int y0 = min(max((int)fy0,0),IH-1), y1 = min(max((int)fy0+1,0),IH-1);
  int x0 = min(max((int)fx0,0),IW-1), x1 = min(max((int)fx0+1,0),IW-1);
  float v00=plane[y0*IW+x0], v01=plane[y0*IW+x1], v10=plane[y1*IW+x0], v11=plane[y1*IW+x1];
  out[idx] = (1.f-ty)*((1.f-tx)*v00+tx*v01) + ty*((1.f-tx)*v10+tx*v11);
}

__global__ __launch_bounds__(256) void k_conv5(const float* in, const float* wf, const float* bf,
                                               float* confr, float* scal){
  int idx = blockIdx.x*256 + threadIdx.x;   // grid exactly B*N/256
  int pix = idx % N_; int b = idx / N_;
  int oy = pix / W_, ox = pix % W_;
  float acc = bf[0];
  for(int ic=0; ic<16; ic++){
    const float* plane = in + ((size_t)b*16+ic)*N_;
    #pragma unroll
    for(int ky=0;ky<3;ky++){
      int iy = min(max(oy+ky-1,0),H_-1);
      const float* row = plane + iy*W_;
      #pragma unroll
      for(int kx=0;kx<3;kx++){
        int ix = min(max(ox+kx-1,0),W_-1);
        acc += row[ix]*wf[(ic*3+ky)*3+kx];
      }
    }
  }
  float c = 0.5f*(tanhf(acc)+1.0f);
  confr[idx]=c;
  float mx = blockReduceMaxF(c);
  if(threadIdx.x==0) atomicMax((int*)&scal[4], __float_as_int(mx));
}

__global__ __launch_bounds__(256) void k_confnorm(const float* confr, const float* scal, float* confout){
  int idx = blockIdx.x*256 + threadIdx.x;   // grid exactly B*N/256
  confout[idx] = confr[idx] / fmaxf(scal[4], 1e-5f);
}

// ---------------- bilateral solver (both batches merged) ----------------

// pass 1: coords/hash per pixel, winner scatter
__global__ __launch_bounds__(256) void k_px1(const float* feat, const float* scal,
                                             int* hpix, int2* cpix2, int* winner){
  int idx = blockIdx.x*256 + threadIdx.x;   // grid exactly 2N/256
  int b = idx / N_, pix = idx % N_;
  int y = pix / W_, x = pix % W_;
  float sF = clampScale(scal[2+b]);
  const float* fb = feat + (size_t)b*3*N_;
  // exact reference eval order, no FMA contraction (coords are integer-binned)
  float R  = __fmul_rn(__fdiv_rn(fb[pix],      sF), 255.0f);
  float G  = __fmul_rn(__fdiv_rn(fb[N_+pix],   sF), 255.0f);
  float Bl = __fmul_rn(__fdiv_rn(fb[2*N_+pix], sF), 255.0f);
  float Y = __fadd_rn(__fadd_rn(__fadd_rn(__fmul_rn(0.299f,R),     __fmul_rn(0.587f,G)),  __fmul_rn(0.114f,Bl)), 0.0f);
  float U = __fadd_rn(__fadd_rn(__fadd_rn(__fmul_rn(-0.168736f,R), __fmul_rn(-0.331264f,G)), __fmul_rn(0.5f,Bl)), 128.0f);
  float V = __fadd_rn(__fadd_rn(__fadd_rn(__fmul_rn(0.5f,R),       __fmul_rn(-0.418688f,G)), __fmul_rn(-0.081312f,Bl)), 128.0f);
  int c[5];
  c[0] = (int)floorf(__fdiv_rn((float)x, 7.0f));
  c[1] = (int)floorf(__fdiv_rn((float)y, 7.0f));
  c[2] = (int)floorf(__fdiv_rn(Y, 8.0f));
  c[3] = (int)floorf(__fdiv_rn(U, 2.0f));
  c[4] = (int)floorf(__fdiv_rn(V, 2.0f));
  unsigned hh = 0;
  #pragma unroll
  for(int d=0;d<5;d++) hh += (unsigned)c[d]*(unsigned)prime(d);
  hh &= TMASK_;
  hpix[idx]=(int)hh;
  // coords are all >=0 and <128 -> 10-bit fields, +/-1 never crosses fields
  cpix2[idx]=make_int2(c[0] | (c[1]<<10) | (c[2]<<20), c[3] | (c[4]<<10));
  atomicMax(&winner[(size_t)b*T_+(int)hh], pix);   // last-writer (max pix) wins = XLA scatter
}

// pass 2: winner pixels claim compact indices (wave-aggregated)
__global__ __launch_bounds__(256) void k_px2(const int* hpix, const int* winner,
                                             int* cidx, int* slot_of, int* count){
  int idx = blockIdx.x*256 + threadIdx.x;   // grid exactly 2N/256
  int b = idx / N_, pix = idx % N_;
  int hh = hpix[idx];
  bool won = (winner[(size_t)b*T_+hh]==pix);
  unsigned long long mk = __ballot(won);
  int lane = threadIdx.x & 63;
  int cnt = __popcll(mk);
  int base = 0;
  if(lane==0 && cnt) base = atomicAdd(&count[b], cnt);
  base = __shfl(base, 0, 64);
  if(won){
    int li = base + __popcll(mk & ((1ull<<lane)-1ull));
    int gi = b*N_ + li;
    cidx[(size_t)b*T_+hh] = gi;
    slot_of[gi] = hh;
  }
}

// pass 3: splat (count, w, w*pred) into compact arrays
__global__ __launch_bounds__(256) void k_px3(const int* hpix, const int* cidx, const float* conf,
                                             const float* pred, float* mcomp, float* splat){
  int idx = blockIdx.x*256 + threadIdx.x;   // grid exactly 2N/256
  int b = idx / N_, pix = idx % N_;
  int gi = cidx[(size_t)b*T_ + hpix[idx]];
  float w = conf[idx];
  const float* pb = pred + (size_t)b*3*N_;
  atomicAdd(&mcomp[gi], 1.0f);
  float* s = splat + 4*(size_t)gi;
  atomicAdd(s+0, __fmul_rn(w, pb[pix]));
  atomicAdd(s+1, __fmul_rn(w, pb[N_+pix]));
  atomicAdd(s+2, __fmul_rn(w, pb[2*N_+pix]));
  atomicAdd(s+3, w);
}

// per compact slot: 10 neighbor compact indices via packed-coord compare
__global__ __launch_bounds__(256) void k_nbr(const int* count, const int* slot_of, const int* winner,
                      const int2* cpix2, const int* cidx, int* nbr, float* n0){
  int i = blockIdx.x*256 + threadIdx.x;     // grid exactly 2N/256
  int b = i / N_, li = i - b*N_;
  if(li >= count[b]) return;
  int hh = slot_of[i];
  const int* wb = winner + (size_t)b*T_;
  const int* cb = cidx   + (size_t)b*T_;
  int2 cp = cpix2[(size_t)b*N_ + wb[hh]];
  #pragma unroll
  for(int j=0;j<10;j++){
    int d=j>>1; int off=(j&1)?1:-1;
    unsigned nh = ((unsigned)hh + (unsigned)(off*prime(d))) & TMASK_;
    int nb = -1;
    int wn = wb[nh];
    if(wn>=0){
      int2 cn = cpix2[(size_t)b*N_ + wn];
      int e0 = cp.x + (d==0?off: d==1?off*(1<<10) : d==2?off*(1<<20) : 0);
      int e1 = cp.y + (d==3?off: d==4?off*(1<<10) : 0);
      if(cn.x==e0 && cn.y==e1) nb = cb[nh];
    }
    nbr[(size_t)i*10+j]=nb;
  }
  n0[i]=1.0f;
}

__global__ __launch_bounds__(256) void k_bisto(const int* count, const int* nbr,
                                               const float* ns, float* nd, const float* mc){
  int i = blockIdx.x*256 + threadIdx.x;
  int b = i / N_, li = i - b*N_;
  if(li >= count[b]) return;
  float nv = ns[i];
  float bv = 10.f*nv;
  #pragma unroll
  for(int j=0;j<10;j++){
    int nb = nbr[(size_t)i*10+j];
    if(nb>=0) bv += ns[nb];
  }
  nd[i] = sqrtf(nv*mc[i]/(bv+1e-12f));
}

// fused mfinal + x0 + A(x0) + r0/z0/p0 + rz0 per-batch reduction
__global__ __launch_bounds__(256) void k_Ar0(const int* count, const int* nbr, const float* n,
                      const float4* splat4, float4* meta4, float4* x4, float4* r4, float4* p4,
                      double* rz0){
  int i = blockIdx.x*256 + threadIdx.x;
  int b = i / N_, li = i - b*N_;
  double a0=0.0,a1=0.0,a2=0.0;
  if(li < count[b]){
    float4 vb4 = splat4[i];
    float wsi = vb4.w;
    float nv = n[i];
    float x0 = vb4.x/(wsi+1e-12f);
    float x1 = vb4.y/(wsi+1e-12f);
    float x2 = vb4.z/(wsi+1e-12f);
    float bv = 10.f*nv;
    float s0=10.f*(nv*x0), s1=10.f*(nv*x1), s2=10.f*(nv*x2);
    #pragma unroll
    for(int j=0;j<10;j++){
      int nb = nbr[(size_t)i*10+j];
      if(nb>=0){
        float4 vbn = splat4[nb];
        float nn = n[nb];
        bv += nn;
        s0 += nn*(vbn.x/(vbn.w+1e-12f));
        s1 += nn*(vbn.y/(vbn.w+1e-12f));
        s2 += nn*(vbn.z/(vbn.w+1e-12f));
      }
    }
    float mfin = nv*bv;
    float Ad = fmaxf(200.0f*(mfin - 10.f*nv*nv) + wsi, 1e-5f);
    float mi = 1.0f/Ad;
    float A0 = 200.f*(mfin*x0 - nv*s0) + wsi*x0;
    float A1 = 200.f*(mfin*x1 - nv*s1) + wsi*x1;
    float A2 = 200.f*(mfin*x2 - nv*s2) + wsi*x2;
    float r0v = vb4.x-A0, r1v = vb4.y-A1, r2v = vb4.z-A2;
    float z0=mi*r0v, z1=mi*r1v, z2=mi*r2v;
    meta4[i]=make_float4(nv,mfin,wsi,mi);
    x4[i]=make_float4(x0,x1,x2,0.f);
    r4[i]=make_float4(r0v,r1v,r2v,mi);
    p4[i]=make_float4(z0,z1,z2,nv);
    a0=(double)r0v*z0; a1=(double)r1v*z1; a2=(double)r2v*z2;
  }
  a0=blockReduceD(a0); a1=blockReduceD(a1); a2=blockReduceD(a2);
  if(threadIdx.x==0){
    atomicAdd(&rz0[b*RZB_+0],     a0);
    atomicAdd(&rz0[b*RZB_+CH_],   a1);
    atomicAdd(&rz0[b*RZB_+2*CH_], a2);
  }
}

// fused p-update + A: p = minv*r + beta*pOld (self & neighbors on the fly), Ap=A(p), p.Ap reduce
__global__ __launch_bounds__(256) void k_Ap(const int* count, const int* nbr, const float4* meta4,
                     const float4* r4, const float4* pOld4, float4* pNew4, float4* Ap4,
                     const double* bNum, const double* bDen, int bstr, double* pAp){
  int i = blockIdx.x*256 + threadIdx.x;
  int b = i / N_, li = i - b*N_;
  double a0=0.0,a1=0.0,a2=0.0;
  float be0=(float)bNum[b*bstr+0]     /((float)bDen[b*bstr+0]     +1e-12f);
  float be1=(float)bNum[b*bstr+CH_]   /((float)bDen[b*bstr+CH_]   +1e-12f);
  float be2=(float)bNum[b*bstr+2*CH_] /((float)bDen[b*bstr+2*CH_] +1e-12f);
  if(li < count[b]){
    float4 mt = meta4[i];
    float nv = mt.x, mfin = mt.y, wsi = mt.z;
    float4 rs = r4[i];
    float4 ps = pOld4[i];
    float p0 = rs.w*rs.x + be0*ps.x;
    float p1 = rs.w*rs.y + be1*ps.y;
    float p2 = rs.w*rs.z + be2*ps.z;
    float s0=10.f*(nv*p0), s1=10.f*(nv*p1), s2=10.f*(nv*p2);
    #pragma unroll
    for(int j=0;j<10;j++){
      int nb = nbr[(size_t)i*10+j];
      if(nb>=0){
        float4 rn = r4[nb];
        float4 pn = pOld4[nb];
        float nn = pn.w;
        s0 += nn*(rn.w*rn.x + be0*pn.x);
        s1 += nn*(rn.w*rn.y + be1*pn.y);
        s2 += nn*(rn.w*rn.z + be2*pn.z);
      }
    }
    float A0 = 200.f*(mfin*p0 - nv*s0) + wsi*p0;
    float A1 = 200.f*(mfin*p1 - nv*s1) + wsi*p1;
    float A2 = 200.f*(mfin*p2 - nv*s2) + wsi*p2;
    pNew4[i]=make_float4(p0,p1,p2,nv);
    Ap4[i]=make_float4(A0,A1,A2,0.f);
    a0=(double)p0*A0; a1=(double)p1*A1; a2=(double)p2*A2;
  }
  a0=blockReduceD(a0); a1=blockReduceD(a1); a2=blockReduceD(a2);
  if(threadIdx.x==0){
    atomicAdd(&pAp[b*PAPB_+0],     a0);
    atomicAdd(&pAp[b*PAPB_+CH_],   a1);
    atomicAdd(&pAp[b*PAPB_+2*CH_], a2);
  }
}

__global__ __launch_bounds__(256) void k_upd1(const int* count, float4* x4, float4* r4,
                       const float4* p4, const float4* Ap4,
                       const double* rzCur, const double* pApC, double* rzNew){
  int i = blockIdx.x*256 + threadIdx.x;
  int b = i / N_, li = i - b*N_;
  double a0=0.0,a1=0.0,a2=0.0;
  float al0=(float)rzCur[b*RZB_+0]     /((float)pApC[b*PAPB_+0]     +1e-12f);
  float al1=(float)rzCur[b*RZB_+CH_]   /((float)pApC[b*PAPB_+CH_]   +1e-12f);
  float al2=(float)rzCur[b*RZB_+2*CH_] /((float)pApC[b*PAPB_+2*CH_] +1e-12f);
  if(li < count[b]){
    float4 xv = x4[i];
    float4 rv = r4[i];
    float4 pv = p4[i];
    float4 av = Ap4[i];
    float mi = rv.w;
    float x0=xv.x+al0*pv.x, x1=xv.y+al1*pv.y, x2=xv.z+al2*pv.z;
    float r0v=rv.x-al0*av.x, r1v=rv.y-al1*av.y, r2v=rv.z-al2*av.z;
    float z0=mi*r0v, z1=mi*r1v, z2=mi*r2v;
    x4[i]=make_float4(x0,x1,x2,0.f);
    r4[i]=make_float4(r0v,r1v,r2v,mi);
    a0=(double)r0v*z0; a1=(double)r1v*z1; a2=(double)r2v*z2;
  }
  a0=blockReduceD(a0); a1=blockReduceD(a1); a2=blockReduceD(a2);
  if(threadIdx.x==0){
    atomicAdd(&rzNew[b*RZB_+0],     a0);
    atomicAdd(&rzNew[b*RZB_+CH_],   a1);
    atomicAdd(&rzNew[b*RZB_+2*CH_], a2);
  }
}

__global__ __launch_bounds__(256) void k_out(const float4* x4, const int* cidx, const int* hpix,
                                             float* out){
  int idx = blockIdx.x*256 + threadIdx.x;   // grid exactly 2N/256
  int b = idx / N_, pix = idx % N_;
  int gi = cidx[(size_t)b*T_ + hpix[idx]];
  float4 xv = x4[gi];
  out[((size_t)(b*3+0))*N_+pix] = xv.x;
  out[((size_t)(b*3+1))*N_+pix] = xv.y;
  out[((size_t)(b*3+2))*N_+pix] = xv.z;
}

// ---------------- host launcher ----------------

extern "C" void kernel_launch(void* const* d_in, const int* in_sizes, int n_in,
                              void* d_out, int out_size, void* d_ws, size_t ws_size,
                              hipStream_t stream){
  const float* image=(const float*)d_in[0];
  const float* feature=(const float*)d_in[1];
  const float* pred=(const float*)d_in[2];
  const float* w1=(const float*)d_in[3];  const float* b1=(const float*)d_in[4];
  const float* g1=(const float*)d_in[5];  const float* be1=(const float*)d_in[6];
  const float* w2=(const float*)d_in[7];  const float* b2=(const float*)d_in[8];
  const float* g2=(const float*)d_in[9];  const float* be2=(const float*)d_in[10];
  const float* wd1=(const float*)d_in[11];const float* bd1=(const float*)d_in[12];
  const float* gd1=(const float*)d_in[13];const float* bed1=(const float*)d_in[14];
  const float* wd2=(const float*)d_in[15];const float* bd2=(const float*)d_in[16];
  const float* gd2=(const float*)d_in[17];const float* bed2=(const float*)d_in[18];
  const float* wf=(const float*)d_in[19]; const float* bf=(const float*)d_in[20];
  float* outp=(float*)d_out;                          // (B,3,H,W)
  float* confout = outp + (size_t)B_*3*N_;            // (B,1,H,W)

  char* wsb=(char*)d_ws;
  float* scal=(float*)wsb;                  // [0..1] imgmax, [2..3] featmax, [4] confmax
  int* count=(int*)(wsb+256);               // count[2]
  double* scalD=(double*)(wsb+4096);        // 3584 doubles (see layout defines)
  double* zeroD = scalD;
  auto rzArr  = [&](int it)->double*{ return scalD + RZ0_  + it*48; };   // batch stride RZB_
  auto pApArr = [&](int it)->double*{ return scalD + PAP0_ + it*48; };   // batch stride PAPB_
  auto gnAcc  = [&](int L)->double*{ return scalD + GN0_ + L*128; };

  size_t off = 65536;
  auto alloc=[&](size_t bytes)->char*{ char* pp=wsb+off; off=(off+bytes+255)&~(size_t)255; return pp; };
  const size_t ALLOC0 = off;

  // CNN region (dead once conf is in d_out; bilateral region overlaps it)
  float* inp  =(float*)alloc((size_t)B_*6*N_*4);
  float* x1   =(float*)alloc((size_t)B_*16*192*256*4);
  float* x2   =(float*)alloc((size_t)B_*16*96*128*4);
  float* dx1  =(float*)alloc((size_t)B_*16*96*128*4);
  float* dx1r =(float*)alloc((size_t)B_*16*192*256*4);
  float* dx2  =(float*)alloc((size_t)B_*16*192*256*4);
  float* dx2r =(float*)alloc((size_t)B_*16*N_*4);
  float* confr=(float*)alloc((size_t)B_*N_*4);

  // bilateral region (reset offset: CNN buffers dead before k_init2 writes here)
  off = ALLOC0;
  int*    winner =(int*)   alloc((size_t)2*T_*4);
  int*    cidx   =(int*)   alloc((size_t)2*T_*4);
  int*    hpix   =(int*)   alloc((size_t)2*N_*4);
  int2*   cpix2  =(int2*)  alloc((size_t)2*N_*8);
  int*    slot_of=(int*)   alloc((size_t)2*N_*4);
  int*    nbr    =(int*)   alloc((size_t)2*N_*10*4);
  float*  mcomp  =(float*) alloc((size_t)2*N_*4);
  float*  nA     =(float*) alloc((size_t)2*N_*4);
  float*  nB     =(float*) alloc((size_t)2*N_*4);
  float4* splat4 =(float4*)alloc((size_t)2*N_*16);   // (b0,b1,b2,wsplat); aliased by Ap4 after Ar0
  float4* meta4  =(float4*)alloc((size_t)2*N_*16);
  float4* x4     =(float4*)alloc((size_t)2*N_*16);
  float4* r4     =(float4*)alloc((size_t)2*N_*16);
  float4* pA4    =(float4*)alloc((size_t)2*N_*16);
  float4* pB4    =(float4*)alloc((size_t)2*N_*16);
  float4* Ap4    = splat4;   // alias: splat4 dead after k_Ar0, Ap4 first written in k_Ap

  dim3 blk(256);

  // ---- init scalars, then CNN ----
  k_init1<<<16,blk,0,stream>>>(scal,count,scalD);
  k_maxes<<<(B_*3*N_)/256,blk,0,stream>>>(image,feature,scal);
  k_prep<<<(B_*6*N_)/256,blk,0,stream>>>(image,pred,scal,inp);

  k_convT<6,0,4,2,true,384,512,192,256><<<(B_*192*256)/256,blk,0,stream>>>(inp,inp,w1,b1,x1,gnAcc(0));
  k_gnapply<<<(B_*16*192*256)/256,blk,0,stream>>>(x1, gnAcc(0), g1, be1, 192*256);

  k_convT<16,0,4,2,true,192,256,96,128><<<(B_*96*128)/256,blk,0,stream>>>(x1,x1,w2,b2,x2,gnAcc(1));
  k_gnapply<<<(B_*16*96*128)/256,blk,0,stream>>>(x2, gnAcc(1), g2, be2, 96*128);

  k_convT<16,0,3,1,false,96,128,96,128><<<(B_*96*128)/256,blk,0,stream>>>(x2,x2,wd1,bd1,dx1,gnAcc(2));
  k_gnapply<<<(B_*16*96*128)/256,blk,0,stream>>>(dx1, gnAcc(2), gd1, bed1, 96*128);

  k_resize<<<(B_*16*192*256)/256,blk,0,stream>>>(dx1, dx1r, 16, 96,128, 192,256);

  k_convT<16,16,3,1,false,192,256,192,256><<<(B_*192*256)/256,blk,0,stream>>>(dx1r,x1,wd2,bd2,dx2,gnAcc(3));
  k_gnapply<<<(B_*16*192*256)/256,blk,0,stream>>>(dx2, gnAcc(3), gd2, bed2, 192*256);

  k_resize<<<(B_*16*N_)/256,blk,0,stream>>>(dx2, dx2r, 16, 192,256, 384,512);

  k_conv5<<<(B_*N_)/256,blk,0,stream>>>(dx2r, wf, bf, confr, scal);
  k_confnorm<<<(B_*N_)/256,blk,0,stream>>>(confr, scal, confout);

  // ---- bilateral solver, both batches at once ----
  k_init2<<<G2T_,blk,0,stream>>>(winner,mcomp,splat4);
  k_px1<<<G2N_,blk,0,stream>>>(feature,scal,hpix,cpix2,winner);
  k_px2<<<G2N_,blk,0,stream>>>(hpix,winner,cidx,slot_of,count);
  k_px3<<<G2N_,blk,0,stream>>>(hpix,cidx,confout,pred,mcomp,(float*)splat4);
  k_nbr<<<G2N_,blk,0,stream>>>(count,slot_of,winner,cpix2,cidx,nbr,nA);

  float* nbuf[2]={nA,nB};
  for(int it=0; it<10; ++it)
    k_bisto<<<G2N_,blk,0,stream>>>(count,nbr,nbuf[it&1],nbuf[(it+1)&1],mcomp);
  float* nfin = nA;   // 10 iterations -> ends in nA

  k_Ar0<<<G2N_,blk,0,stream>>>(count,nbr,nfin,splat4,meta4,x4,r4,pA4,rzArr(0));

  float4* pbuf[2]={pA4,pB4};
  for(int it=0; it<12; ++it){
    const double* bN = (it==0) ? zeroD : rzArr(it);
    const double* bD = (it==0) ? zeroD : rzArr(it-1);
    int bstr = (it==0) ? 0 : RZB_;
    k_Ap<<<G2N_,blk,0,stream>>>(count,nbr,meta4,r4,pbuf[it&1],pbuf[(it+1)&1],Ap4,bN,bD,bstr,pApArr(it));
    k_upd1<<<G2N_,blk,0,stream>>>(count,x4,r4,pbuf[(it+1)&1],Ap4,rzArr(it),pApArr(it),rzArr(it+1));
  }
  k_out<<<G2N_,blk,0,stream>>>(x4,cidx,hpix,outp);

  (void)in_sizes; (void)n_in; (void)out_size; (void)ws_size;
}

// Round 7
// 935.141 us; speedup vs baseline: 9.6717x; 1.1545x over previous
//
#include <hip/hip_runtime.h>

#define H_ 384
#define W_ 512
#define N_ (H_*W_)        // 196608
#define B_ 2
#define T_ 1048576
#define TMASK_ 0xFFFFFu
#define G2N_ ((2*N_)/256) // 1536
#define CH_ 16            // channel stride (doubles) in padded accumulators (128B)
// scalD layout (doubles):
//   [0..47]    zeroD (stays 0; beta num/den at it==0)
//   rz  [b][it] at 64   + b*672 + it*48   (it=0..13)
//   pAp [b][it] at 1408 + b*624 + it*48   (it=0..12)
//   GN acc      at 2688 + L*128 + bg*32 (+0 sum, +16 sumsq)
#define RZ0_ 64
#define RZB_ 672
#define PAP0_ 1408
#define PAPB_ 624
#define GN0_ 2688

__device__ __forceinline__ int prime(int d){
  switch(d){
    case 0: return 73856093;
    case 1: return 19349663;
    case 2: return 83492791;
    case 3: return 49979687;
    default: return 24036583;
  }
}

__device__ __forceinline__ float clampScale(float s){ return fminf(fmaxf(s,1e-5f),1.0f); }

__device__ __forceinline__ double blockReduceD(double v){
  __shared__ double sh[4];
  for(int s=32;s>0;s>>=1) v += __shfl_down(v,s,64);
  int lane=threadIdx.x&63, w=threadIdx.x>>6;
  if(lane==0) sh[w]=v;
  __syncthreads();
  double r = sh[0]+sh[1]+sh[2]+sh[3];
  __syncthreads();
  return r;
}
__device__ __forceinline__ float blockReduceMaxF(float v){
  __shared__ float sh[4];
  for(int s=32;s>0;s>>=1) v = fmaxf(v,__shfl_down(v,s,64));
  int lane=threadIdx.x&63, w=threadIdx.x>>6;
  if(lane==0) sh[w]=v;
  __syncthreads();
  float r = fmaxf(fmaxf(sh[0],sh[1]),fmaxf(sh[2],sh[3]));
  __syncthreads();
  return r;
}

// ---------------- CNN kernels ----------------

// grid-stride float4 max; grid 128 blocks
__global__ __launch_bounds__(256) void k_maxes(const float4* img4, const float4* feat4, float* scal){
  const int PB = (3*N_)/4;   // per-batch float4 count
  for(int b=0;b<2;b++){
    float lm=0.f, lf=0.f;
    for(int idx = blockIdx.x*256+threadIdx.x; idx<PB; idx += gridDim.x*256){
      float4 a=img4[(size_t)b*PB+idx], c=feat4[(size_t)b*PB+idx];
      lm=fmaxf(lm, fmaxf(fmaxf(a.x,a.y),fmaxf(a.z,a.w)));
      lf=fmaxf(lf, fmaxf(fmaxf(c.x,c.y),fmaxf(c.z,c.w)));
    }
    lm=blockReduceMaxF(lm); lf=blockReduceMaxF(lf);
    if(threadIdx.x==0){
      atomicMax((int*)&scal[b],   __float_as_int(lm));
      atomicMax((int*)&scal[2+b], __float_as_int(lf));
    }
  }
}

template<bool SCALEA,int NCH,int IC,int K,int S,bool EDGE,int IH,int IW>
__device__ __forceinline__ void conv_accum(const float* __restrict__ plane0, int icBase, float sA,
                                           int oy, int ox, const float* wlds, float acc[16]){
  for(int ic=0; ic<NCH; ic++){
    const float* plane = plane0 + (size_t)ic*IH*IW;
    #pragma unroll
    for(int ky=0;ky<K;ky++){
      int iy = oy*S + ky - 1;
      int cy = min(max(iy,0),IH-1);
      bool yin = (iy>=0)&&(iy<IH);
      const float* row = plane + cy*IW;
      #pragma unroll
      for(int kx=0;kx<K;kx++){
        int ix = ox*S + kx - 1;
        float v;
        if(EDGE){
          int cx = min(max(ix,0),IW-1);
          v = row[cx];
        } else {
          v = (yin && ix>=0 && ix<IW) ? row[ix] : 0.f;
        }
        if(SCALEA) v = v / sA;   // inline max-normalize (identical IEEE div to k_prep)
        const float4* wp = (const float4*)&wlds[(((icBase+ic)*K+ky)*K+kx)*16];
        #pragma unroll
        for(int q=0;q<4;q++){
          float4 w4 = wp[q];
          acc[4*q+0] += v*w4.x;
          acc[4*q+1] += v*w4.y;
          acc[4*q+2] += v*w4.z;
          acc[4*q+3] += v*w4.w;
        }
      }
    }
  }
}

// conv OC=16, one thread = one pixel all 16 oc; weights transposed into LDS;
// fused GroupNorm partial sums into gnacc. Optional inline /s normalize of input A.
template<bool SCALEA,int ICA,int ICB,int K,int S,bool EDGE,int IH,int IW,int OH,int OW>
__global__ __launch_bounds__(256) void k_convT(const float* __restrict__ inA, const float* __restrict__ inB,
                        const float* __restrict__ wt, const float* __restrict__ bias,
                        float* __restrict__ out, double* gnacc, const float* scal){
  constexpr int IC = ICA+ICB;
  __shared__ float wlds[IC*K*K*16];
  __shared__ float blds[16];
  for(int i=threadIdx.x; i<IC*K*K*16; i+=256){
    int oc=i&15, ickk=i>>4;
    wlds[i] = wt[oc*IC*K*K + ickk];
  }
  if(threadIdx.x<16) blds[threadIdx.x]=bias[threadIdx.x];
  __syncthreads();
  int idx = blockIdx.x*256+threadIdx.x;      // grid exactly B*OH*OW/256
  int ox = idx % OW; int t=idx/OW; int oy=t%OH; int b=t/OH;
  float sA = SCALEA ? clampScale(scal[b]) : 1.0f;
  float acc[16];
  #pragma unroll
  for(int oc=0;oc<16;oc++) acc[oc]=0.f;
  conv_accum<SCALEA,ICA,IC,K,S,EDGE,IH,IW>(inA + (size_t)b*ICA*IH*IW, 0, sA, oy, ox, wlds, acc);
  if(ICB>0)
    conv_accum<false,(ICB>0?ICB:1),IC,K,S,EDGE,IH,IW>(inB + (size_t)b*ICB*IH*IW, ICA, 1.0f, oy, ox, wlds, acc);
  double sl=0.0,s2l=0.0,sh=0.0,s2h=0.0;
  #pragma unroll
  for(int oc=0;oc<16;oc++){
    float vv = acc[oc] + blds[oc];
    out[(((size_t)b*16+oc)*OH+oy)*OW+ox] = vv;
    if(oc<8){ sl += vv; s2l += (double)vv*(double)vv; }
    else    { sh += vv; s2h += (double)vv*(double)vv; }
  }
  sl=blockReduceD(sl); s2l=blockReduceD(s2l);
  sh=blockReduceD(sh); s2h=blockReduceD(s2h);
  if(threadIdx.x==0){
    atomicAdd(&gnacc[(b*2+0)*32],    sl);
    atomicAdd(&gnacc[(b*2+0)*32+16], s2l);
    atomicAdd(&gnacc[(b*2+1)*32],    sh);
    atomicAdd(&gnacc[(b*2+1)*32+16], s2h);
  }
}

__global__ __launch_bounds__(256) void k_gnapply(float* x, const double* acc, const float* gamma, const float* beta, int HW){
  int idx = blockIdx.x*256 + threadIdx.x;      // grid exactly B*16*HW/256
  int c = (idx/HW)%16; int b = idx/(16*HW);
  int bg = b*2 + (c>>3);
  double len = 8.0*(double)HW;
  double s = acc[bg*32], s2 = acc[bg*32+16];
  double mean = s/len;
  double var = s2/len - mean*mean;
  float rstd = (float)(1.0/sqrt(var + 1e-5));
  float mf = (float)mean;
  float v = (x[idx]-mf)*rstd*gamma[c]+beta[c];
  x[idx] = fmaxf(v,0.f);
}

// fused GN(+relu) applied per tap, then half-pixel bilinear resize (edge clamp)
__global__ __launch_bounds__(256) void k_resizeGN(const float* in, float* out, const double* acc,
                                                  const float* gamma, const float* beta,
                                                  int IH, int IW, int OH, int OW){
  int idx = blockIdx.x*256 + threadIdx.x;
  int total = B_*16*OH*OW;
  if(idx>=total) return;
  int ox = idx%OW; int t=idx/OW; int oy=t%OH; t/=OH;   // t = b*16+c
  int c = t%16, b = t/16; int bg = b*2 + (c>>3);
  double len = 8.0*(double)(IH*IW);
  double s = acc[bg*32], s2 = acc[bg*32+16];
  double mean = s/len;
  double var = s2/len - mean*mean;
  float rstd = (float)(1.0/sqrt(var + 1e-5));
  float mf = (float)mean;
  float g = gamma[c], be = beta[c];
  const float* plane = in + (size_t)t*IH*IW;
  float sy = (float)IH/(float)OH, sx=(float)IW/(float)OW;
  float fy = (oy+0.5f)*sy-0.5f, fx=(ox+0.5f)*sx-0.5f;
  float fy0 = floorf(fy), fx0=floorf(fx);
  float ty = fy-fy0, tx = fx-fx0;
  int y0 = min(max((int)fy0,0),IH-1), y1 = min(max((int)fy0+1,0),IH-1);
  int x0 = min(max((int)fx0,0),IW-1), x1 = min(max((int)fx0+1,0),IW-1);
  float v00=fmaxf((plane[y0*IW+x0]-mf)*rstd*g+be,0.f);
  float v01=fmaxf((plane[y0*IW+x1]-mf)*rstd*g+be,0.f);
  float v10=fmaxf((plane[y1*IW+x0]-mf)*rstd*g+be,0.f);
  float v11=fmaxf((plane[y1*IW+x1]-mf)*rstd*g+be,0.f);
  out[idx] = (1.f-ty)*((1.f-tx)*v00+tx*v01) + ty*((1.f-tx)*v10+tx*v11);
}

__global__ __launch_bounds__(256) void k_conv5(const float* in, const float* wf, const float* bf,
                                               float* confr, float* scal){
  int idx = blockIdx.x*256 + threadIdx.x;   // grid exactly B*N/256
  int pix = idx % N_; int b = idx / N_;
  int oy = pix / W_, ox = pix % W_;
  float acc = bf[0];
  for(int ic=0; ic<16; ic++){
    const float* plane = in + ((size_t)b*16+ic)*N_;
    #pragma unroll
    for(int ky=0;ky<3;ky++){
      int iy = min(max(oy+ky-1,0),H_-1);
      const float* row = plane + iy*W_;
      #pragma unroll
      for(int kx=0;kx<3;kx++){
        int ix = min(max(ox+kx-1,0),W_-1);
        acc += row[ix]*wf[(ic*3+ky)*3+kx];
      }
    }
  }
  float c = 0.5f*(tanhf(acc)+1.0f);
  confr[idx]=c;
  float mx = blockReduceMaxF(c);
  if(threadIdx.x==0) atomicMax((int*)&scal[4], __float_as_int(mx));
}

// ---------------- bilateral solver setup (both batches merged) ----------------

__global__ __launch_bounds__(256) void k_px1(const float* feat, const float* scal,
                                             int* hpix, int2* cpix2, int* winner){
  int idx = blockIdx.x*256 + threadIdx.x;   // grid exactly 2N/256
  int b = idx / N_, pix = idx % N_;
  int y = pix / W_, x = pix % W_;
  float sF = clampScale(scal[2+b]);
  const float* fb = feat + (size_t)b*3*N_;
  // exact reference eval order, no FMA contraction (coords are integer-binned)
  float R  = __fmul_rn(__fdiv_rn(fb[pix],      sF), 255.0f);
  float G  = __fmul_rn(__fdiv_rn(fb[N_+pix],   sF), 255.0f);
  float Bl = __fmul_rn(__fdiv_rn(fb[2*N_+pix], sF), 255.0f);
  float Y = __fadd_rn(__fadd_rn(__fadd_rn(__fmul_rn(0.299f,R),     __fmul_rn(0.587f,G)),  __fmul_rn(0.114f,Bl)), 0.0f);
  float U = __fadd_rn(__fadd_rn(__fadd_rn(__fmul_rn(-0.168736f,R), __fmul_rn(-0.331264f,G)), __fmul_rn(0.5f,Bl)), 128.0f);
  float V = __fadd_rn(__fadd_rn(__fadd_rn(__fmul_rn(0.5f,R),       __fmul_rn(-0.418688f,G)), __fmul_rn(-0.081312f,Bl)), 128.0f);
  int c[5];
  c[0] = (int)floorf(__fdiv_rn((float)x, 7.0f));
  c[1] = (int)floorf(__fdiv_rn((float)y, 7.0f));
  c[2] = (int)floorf(__fdiv_rn(Y, 8.0f));
  c[3] = (int)floorf(__fdiv_rn(U, 2.0f));
  c[4] = (int)floorf(__fdiv_rn(V, 2.0f));
  unsigned hh = 0;
  #pragma unroll
  for(int d=0;d<5;d++) hh += (unsigned)c[d]*(unsigned)prime(d);
  hh &= TMASK_;
  hpix[idx]=(int)hh;
  cpix2[idx]=make_int2(c[0] | (c[1]<<10) | (c[2]<<20), c[3] | (c[4]<<10));
  atomicMax(&winner[(size_t)b*T_+(int)hh], pix);   // last-writer (max pix) wins = XLA scatter
}

__global__ __launch_bounds__(256) void k_px2(const int* hpix, const int* winner,
                                             int* cidx, int* slot_of, int* count){
  int idx = blockIdx.x*256 + threadIdx.x;   // grid exactly 2N/256
  int b = idx / N_, pix = idx % N_;
  int hh = hpix[idx];
  bool won = (winner[(size_t)b*T_+hh]==pix);
  unsigned long long mk = __ballot(won);
  int lane = threadIdx.x & 63;
  int cnt = __popcll(mk);
  int base = 0;
  if(lane==0 && cnt) base = atomicAdd(&count[b], cnt);
  base = __shfl(base, 0, 64);
  if(won){
    int li = base + __popcll(mk & ((1ull<<lane)-1ull));
    int gi = b*N_ + li;
    cidx[(size_t)b*T_+hh] = gi;
    slot_of[gi] = hh;
  }
}

// conf normalize (fused from k_confnorm) + splat (count, w, w*pred) into compact arrays
__global__ __launch_bounds__(256) void k_px3(const int* hpix, const int* cidx, const float* confr,
                                             const float* scal, float* confout,
                                             const float* pred, float* mcomp, float* splat){
  int idx = blockIdx.x*256 + threadIdx.x;   // grid exactly 2N/256
  int b = idx / N_, pix = idx % N_;
  int gi = cidx[(size_t)b*T_ + hpix[idx]];
  float w = confr[idx] / fmaxf(scal[4], 1e-5f);
  confout[idx] = w;
  const float* pb = pred + (size_t)b*3*N_;
  atomicAdd(&mcomp[gi], 1.0f);
  float* s = splat + 4*(size_t)gi;
  atomicAdd(s+0, __fmul_rn(w, pb[pix]));
  atomicAdd(s+1, __fmul_rn(w, pb[N_+pix]));
  atomicAdd(s+2, __fmul_rn(w, pb[2*N_+pix]));
  atomicAdd(s+3, w);
}

// fused neighbor-table build (SoA nbr[j*2N+i]) + first bisto iteration (n0 = 1)
__global__ __launch_bounds__(256) void k_bisto0(const int* count, const int* slot_of, const int* winner,
                      const int2* cpix2, const int* cidx, int* nbr, const float* mcomp, float* nd){
  int i = blockIdx.x*256 + threadIdx.x;     // grid exactly 2N/256
  int b = i / N_, li = i - b*N_;
  if(li >= count[b]) return;
  int hh = slot_of[i];
  const int* wb = winner + (size_t)b*T_;
  const int* cb = cidx   + (size_t)b*T_;
  int2 cp = cpix2[(size_t)b*N_ + wb[hh]];
  float bv = 10.f;                          // 10*n  with n=1
  #pragma unroll
  for(int j=0;j<10;j++){
    int d=j>>1; int off=(j&1)?1:-1;
    unsigned nh = ((unsigned)hh + (unsigned)(off*prime(d))) & TMASK_;
    int nb = -1;
    int wn = wb[nh];
    if(wn>=0){
      int2 cn = cpix2[(size_t)b*N_ + wn];
      int e0 = cp.x + (d==0?off: d==1?off*(1<<10) : d==2?off*(1<<20) : 0);
      int e1 = cp.y + (d==3?off: d==4?off*(1<<10) : 0);
      if(cn.x==e0 && cn.y==e1) nb = cb[nh];
    }
    nbr[(size_t)j*(2*N_)+i]=nb;
    if(nb>=0) bv += 1.0f;                   // neighbor n = 1
  }
  nd[i] = sqrtf(1.0f*mcomp[i]/(bv+1e-12f));
}

__global__ __launch_bounds__(256) void k_bisto(const int* count, const int* nbr,
                                               const float* ns, float* nd, const float* mc){
  int i = blockIdx.x*256 + threadIdx.x;
  int b = i / N_, li = i - b*N_;
  if(li >= count[b]) return;
  float nv = ns[i];
  float bv = 10.f*nv;
  #pragma unroll
  for(int j=0;j<10;j++){
    int nb = nbr[(size_t)j*(2*N_)+i];
    if(nb>=0) bv += ns[nb];
  }
  nd[i] = sqrtf(nv*mc[i]/(bv+1e-12f));
}

// fused mfinal + x0 + A(x0) + r0/z0/p0 + rz0 per-batch reduction
__global__ __launch_bounds__(256) void k_Ar0(const int* count, const int* nbr, const float* n,
                      const float4* splat4, float4* meta4, float4* x4, float4* r4, float4* p4,
                      double* rz0){
  int i = blockIdx.x*256 + threadIdx.x;
  int b = i / N_, li = i - b*N_;
  double a0=0.0,a1=0.0,a2=0.0;
  if(li < count[b]){
    float4 vb4 = splat4[i];
    float wsi = vb4.w;
    float nv = n[i];
    float x0 = vb4.x/(wsi+1e-12f);
    float x1 = vb4.y/(wsi+1e-12f);
    float x2 = vb4.z/(wsi+1e-12f);
    float bv = 10.f*nv;
    float s0=10.f*(nv*x0), s1=10.f*(nv*x1), s2=10.f*(nv*x2);
    #pragma unroll
    for(int j=0;j<10;j++){
      int nb = nbr[(size_t)j*(2*N_)+i];
      if(nb>=0){
        float4 vbn = splat4[nb];
        float nn = n[nb];
        bv += nn;
        s0 += nn*(vbn.x/(vbn.w+1e-12f));
        s1 += nn*(vbn.y/(vbn.w+1e-12f));
        s2 += nn*(vbn.z/(vbn.w+1e-12f));
      }
    }
    float mfin = nv*bv;
    float Ad = fmaxf(200.0f*(mfin - 10.f*nv*nv) + wsi, 1e-5f);
    float mi = 1.0f/Ad;
    float A0 = 200.f*(mfin*x0 - nv*s0) + wsi*x0;
    float A1 = 200.f*(mfin*x1 - nv*s1) + wsi*x1;
    float A2 = 200.f*(mfin*x2 - nv*s2) + wsi*x2;
    float r0v = vb4.x-A0, r1v = vb4.y-A1, r2v = vb4.z-A2;
    float z0=mi*r0v, z1=mi*r1v, z2=mi*r2v;
    meta4[i]=make_float4(nv,mfin,wsi,mi);
    x4[i]=make_float4(x0,x1,x2,0.f);
    r4[i]=make_float4(r0v,r1v,r2v,mi);
    p4[i]=make_float4(z0,z1,z2,nv);
    a0=(double)r0v*z0; a1=(double)r1v*z1; a2=(double)r2v*z2;
  }
  a0=blockReduceD(a0); a1=blockReduceD(a1); a2=blockReduceD(a2);
  if(threadIdx.x==0){
    atomicAdd(&rz0[b*RZB_+0],     a0);
    atomicAdd(&rz0[b*RZB_+CH_],   a1);
    atomicAdd(&rz0[b*RZB_+2*CH_], a2);
  }
}

// fused p-update + A: p = minv*r + beta*pOld (self & neighbors on the fly), Ap=A(p), p.Ap reduce
__global__ __launch_bounds__(256) void k_Ap(const int* count, const int* nbr, const float4* meta4,
                     const float4* r4, const float4* pOld4, float4* pNew4, float4* Ap4,
                     const double* bNum, const double* bDen, int bstr, double* pAp){
  int i = blockIdx.x*256 + threadIdx.x;
  int b = i / N_, li = i - b*N_;
  double a0=0.0,a1=0.0,a2=0.0;
  float be0=(float)bNum[b*bstr+0]     /((float)bDen[b*bstr+0]     +1e-12f);
  float be1=(float)bNum[b*bstr+CH_]   /((float)bDen[b*bstr+CH_]   +1e-12f);
  float be2=(float)bNum[b*bstr+2*CH_] /((float)bDen[b*bstr+2*CH_] +1e-12f);
  if(li < count[b]){
    float4 mt = meta4[i];
    float nv = mt.x, mfin = mt.y, wsi = mt.z;
    float4 rs = r4[i];
    float4 ps = pOld4[i];
    float p0 = rs.w*rs.x + be0*ps.x;
    float p1 = rs.w*rs.y + be1*ps.y;
    float p2 = rs.w*rs.z + be2*ps.z;
    float s0=10.f*(nv*p0), s1=10.f*(nv*p1), s2=10.f*(nv*p2);
    #pragma unroll
    for(int j=0;j<10;j++){
      int nb = nbr[(size_t)j*(2*N_)+i];
      if(nb>=0){
        float4 rn = r4[nb];
        float4 pn = pOld4[nb];
        float nn = pn.w;
        s0 += nn*(rn.w*rn.x + be0*pn.x);
        s1 += nn*(rn.w*rn.y + be1*pn.y);
        s2 += nn*(rn.w*rn.z + be2*pn.z);
      }
    }
    float A0 = 200.f*(mfin*p0 - nv*s0) + wsi*p0;
    float A1 = 200.f*(mfin*p1 - nv*s1) + wsi*p1;
    float A2 = 200.f*(mfin*p2 - nv*s2) + wsi*p2;
    pNew4[i]=make_float4(p0,p1,p2,nv);
    Ap4[i]=make_float4(A0,A1,A2,0.f);
    a0=(double)p0*A0; a1=(double)p1*A1; a2=(double)p2*A2;
  }
  a0=blockReduceD(a0); a1=blockReduceD(a1); a2=blockReduceD(a2);
  if(threadIdx.x==0){
    atomicAdd(&pAp[b*PAPB_+0],     a0);
    atomicAdd(&pAp[b*PAPB_+CH_],   a1);
    atomicAdd(&pAp[b*PAPB_+2*CH_], a2);
  }
}

__global__ __launch_bounds__(256) void k_upd1(const int* count, float4* x4, float4* r4,
                       const float4* p4, const float4* Ap4,
                       const double* rzCur, const double* pApC, double* rzNew){
  int i = blockIdx.x*256 + threadIdx.x;
  int b = i / N_, li = i - b*N_;
  double a0=0.0,a1=0.0,a2=0.0;
  float al0=(float)rzCur[b*RZB_+0]     /((float)pApC[b*PAPB_+0]     +1e-12f);
  float al1=(float)rzCur[b*RZB_+CH_]   /((float)pApC[b*PAPB_+CH_]   +1e-12f);
  float al2=(float)rzCur[b*RZB_+2*CH_] /((float)pApC[b*PAPB_+2*CH_] +1e-12f);
  if(li < count[b]){
    float4 xv = x4[i];
    float4 rv = r4[i];
    float4 pv = p4[i];
    float4 av = Ap4[i];
    float mi = rv.w;
    float x0=xv.x+al0*pv.x, x1=xv.y+al1*pv.y, x2=xv.z+al2*pv.z;
    float r0v=rv.x-al0*av.x, r1v=rv.y-al1*av.y, r2v=rv.z-al2*av.z;
    float z0=mi*r0v, z1=mi*r1v, z2=mi*r2v;
    x4[i]=make_float4(x0,x1,x2,0.f);
    r4[i]=make_float4(r0v,r1v,r2v,mi);
    a0=(double)r0v*z0; a1=(double)r1v*z1; a2=(double)r2v*z2;
  }
  a0=blockReduceD(a0); a1=blockReduceD(a1); a2=blockReduceD(a2);
  if(threadIdx.x==0){
    atomicAdd(&rzNew[b*RZB_+0],     a0);
    atomicAdd(&rzNew[b*RZB_+CH_],   a1);
    atomicAdd(&rzNew[b*RZB_+2*CH_], a2);
  }
}

__global__ __launch_bounds__(256) void k_out(const float4* x4, const int* cidx, const int* hpix,
                                             float* out){
  int idx = blockIdx.x*256 + threadIdx.x;   // grid exactly 2N/256
  int b = idx / N_, pix = idx % N_;
  int gi = cidx[(size_t)b*T_ + hpix[idx]];
  float4 xv = x4[gi];
  out[((size_t)(b*3+0))*N_+pix] = xv.x;
  out[((size_t)(b*3+1))*N_+pix] = xv.y;
  out[((size_t)(b*3+2))*N_+pix] = xv.z;
}

// ---------------- host launcher ----------------

extern "C" void kernel_launch(void* const* d_in, const int* in_sizes, int n_in,
                              void* d_out, int out_size, void* d_ws, size_t ws_size,
                              hipStream_t stream){
  const float* image=(const float*)d_in[0];
  const float* feature=(const float*)d_in[1];
  const float* pred=(const float*)d_in[2];
  const float* w1=(const float*)d_in[3];  const float* b1=(const float*)d_in[4];
  const float* g1=(const float*)d_in[5];  const float* be1=(const float*)d_in[6];
  const float* w2=(const float*)d_in[7];  const float* b2=(const float*)d_in[8];
  const float* g2=(const float*)d_in[9];  const float* be2=(const float*)d_in[10];
  const float* wd1=(const float*)d_in[11];const float* bd1=(const float*)d_in[12];
  const float* gd1=(const float*)d_in[13];const float* bed1=(const float*)d_in[14];
  const float* wd2=(const float*)d_in[15];const float* bd2=(const float*)d_in[16];
  const float* gd2=(const float*)d_in[17];const float* bed2=(const float*)d_in[18];
  const float* wf=(const float*)d_in[19]; const float* bf=(const float*)d_in[20];
  float* outp=(float*)d_out;                          // (B,3,H,W)
  float* confout = outp + (size_t)B_*3*N_;            // (B,1,H,W)

  char* wsb=(char*)d_ws;
  float* scal=(float*)wsb;                  // [0..1] imgmax, [2..3] featmax, [4] confmax
  int* count=(int*)(wsb+256);               // count[2]
  double* scalD=(double*)(wsb+4096);        // 3584 doubles (see layout defines)
  double* zeroD = scalD;
  auto rzArr  = [&](int it)->double*{ return scalD + RZ0_  + it*48; };   // batch stride RZB_
  auto pApArr = [&](int it)->double*{ return scalD + PAP0_ + it*48; };   // batch stride PAPB_
  auto gnAcc  = [&](int L)->double*{ return scalD + GN0_ + L*128; };

  size_t off = 65536;
  auto alloc=[&](size_t bytes)->char*{ char* pp=wsb+off; off=(off+bytes+255)&~(size_t)255; return pp; };
  const size_t ALLOC0 = off;

  // CNN region (dead once conf is in confr/d_out; bilateral region overlaps it)
  float* x1   =(float*)alloc((size_t)B_*16*192*256*4);
  float* x2   =(float*)alloc((size_t)B_*16*96*128*4);
  float* dx1  =(float*)alloc((size_t)B_*16*96*128*4);
  float* dx1r =(float*)alloc((size_t)B_*16*192*256*4);
  float* dx2  =(float*)alloc((size_t)B_*16*192*256*4);
  float* dx2r =(float*)alloc((size_t)B_*16*N_*4);

  // bilateral region (reset offset: CNN buffers dead before the solver memsets/writes)
  off = ALLOC0;
  int*    winner =(int*)   alloc((size_t)2*T_*4);
  int*    cidx   =(int*)   alloc((size_t)2*T_*4);
  int*    hpix   =(int*)   alloc((size_t)2*N_*4);
  int2*   cpix2  =(int2*)  alloc((size_t)2*N_*8);
  int*    slot_of=(int*)   alloc((size_t)2*N_*4);
  int*    nbr    =(int*)   alloc((size_t)2*N_*10*4);
  float*  mcomp  =(float*) alloc((size_t)2*N_*4);    // mcomp+splat4 contiguous for one memset
  float4* splat4 =(float4*)alloc((size_t)2*N_*16);   // (b0,b1,b2,wsplat)
  float*  nA     =(float*) alloc((size_t)2*N_*4);
  float*  nB     =(float*) alloc((size_t)2*N_*4);
  float4* meta4  =(float4*)alloc((size_t)2*N_*16);
  float4* x4     =(float4*)alloc((size_t)2*N_*16);
  float4* r4     =(float4*)alloc((size_t)2*N_*16);
  float4* pA4    =(float4*)alloc((size_t)2*N_*16);
  float4* pB4    =(float4*)alloc((size_t)2*N_*16);
  float4* Ap4    = splat4;        // alias: splat4 dead after k_Ar0
  float*  confr  = (float*)pB4;   // alias: pB4 first written in k_Ap it=0, confr dead after px3

  dim3 blk(256);

  // ---- init scalars (scal, count, scalD in one block) ----
  hipMemsetAsync(wsb, 0, 32768, stream);

  // ---- CNN ----
  k_maxes<<<128,blk,0,stream>>>((const float4*)image,(const float4*)feature,scal);

  k_convT<true,3,3,4,2,true,384,512,192,256><<<(B_*192*256)/256,blk,0,stream>>>(image,pred,w1,b1,x1,gnAcc(0),scal);
  k_gnapply<<<(B_*16*192*256)/256,blk,0,stream>>>(x1, gnAcc(0), g1, be1, 192*256);

  k_convT<false,16,0,4,2,true,192,256,96,128><<<(B_*96*128)/256,blk,0,stream>>>(x1,x1,w2,b2,x2,gnAcc(1),scal);
  k_gnapply<<<(B_*16*96*128)/256,blk,0,stream>>>(x2, gnAcc(1), g2, be2, 96*128);

  k_convT<false,16,0,3,1,false,96,128,96,128><<<(B_*96*128)/256,blk,0,stream>>>(x2,x2,wd1,bd1,dx1,gnAcc(2),scal);
  k_resizeGN<<<(B_*16*192*256)/256,blk,0,stream>>>(dx1, dx1r, gnAcc(2), gd1, bed1, 96,128, 192,256);

  k_convT<false,16,16,3,1,false,192,256,192,256><<<(B_*192*256)/256,blk,0,stream>>>(dx1r,x1,wd2,bd2,dx2,gnAcc(3),scal);
  k_resizeGN<<<(B_*16*N_)/256,blk,0,stream>>>(dx2, dx2r, gnAcc(3), gd2, bed2, 192,256, 384,512);

  k_conv5<<<(B_*N_)/256,blk,0,stream>>>(dx2r, wf, bf, confr, scal);

  // ---- bilateral solver setup ----
  hipMemsetAsync(winner, 0xFF, (size_t)2*T_*4, stream);                      // winner = -1
  hipMemsetAsync(mcomp, 0, (size_t)2*N_*4 + (size_t)2*N_*16, stream);        // mcomp + splat4 = 0
  k_px1<<<G2N_,blk,0,stream>>>(feature,scal,hpix,cpix2,winner);
  k_px2<<<G2N_,blk,0,stream>>>(hpix,winner,cidx,slot_of,count);
  k_px3<<<G2N_,blk,0,stream>>>(hpix,cidx,confr,scal,confout,pred,mcomp,(float*)splat4);

  // ---- bistochastization: fused nbr-build + it0, then 9 more ----
  k_bisto0<<<G2N_,blk,0,stream>>>(count,slot_of,winner,cpix2,cidx,nbr,mcomp,nA);
  for(int it=1; it<10; ++it){
    float* src = (it&1) ? nA : nB;
    float* dst = (it&1) ? nB : nA;
    k_bisto<<<G2N_,blk,0,stream>>>(count,nbr,src,dst,mcomp);
  }
  float* nfin = nB;   // it9 (odd) wrote nB

  k_Ar0<<<G2N_,blk,0,stream>>>(count,nbr,nfin,splat4,meta4,x4,r4,pA4,rzArr(0));

  float4* pbuf[2]={pA4,pB4};
  for(int it=0; it<12; ++it){
    const double* bN = (it==0) ? zeroD : rzArr(it);
    const double* bD = (it==0) ? zeroD : rzArr(it-1);
    int bstr = (it==0) ? 0 : RZB_;
    k_Ap<<<G2N_,blk,0,stream>>>(count,nbr,meta4,r4,pbuf[it&1],pbuf[(it+1)&1],Ap4,bN,bD,bstr,pApArr(it));
    k_upd1<<<G2N_,blk,0,stream>>>(count,x4,r4,pbuf[(it+1)&1],Ap4,rzArr(it),pApArr(it),rzArr(it+1));
  }
  k_out<<<G2N_,blk,0,stream>>>(x4,cidx,hpix,outp);

  (void)in_sizes; (void)n_in; (void)out_size; (void)ws_size;
}